// Round 1
// 423.686 us; speedup vs baseline: 1.0401x; 1.0401x over previous
//
#include <hip/hip_runtime.h>
#include <stdint.h>

// Problem constants
#define B_  16
#define N_  1024
#define C_  1024
#define H_  16
#define D_  64
#define P_  16
#define M_  1040           // P + N
#define MP_ 1088           // M padded to 17*64

typedef __attribute__((ext_vector_type(8))) short short8;   // 8 bf16 = 4 VGPRs
typedef __attribute__((ext_vector_type(4))) float f32x4;    // MFMA C/D frag

__device__ __forceinline__ unsigned short f2bf(float f) {
  unsigned int u = __float_as_uint(f);
  u += 0x7fffu + ((u >> 16) & 1u);          // RNE
  return (unsigned short)(u >> 16);
}

// async global->LDS, 16B per lane. LDS dest must be wave-uniform base (+lane*16 implicit).
__device__ __forceinline__ void async_cp16(void* lds, const void* g) {
  __builtin_amdgcn_global_load_lds(
      (__attribute__((address_space(1))) void*)(void*)g,
      (__attribute__((address_space(3))) void*)lds,
      16, 0, 0);
}

// ---------------- prep kernels (merged: 2 launches) ----------------

// blocks [0,16384): x fp32->bf16 cast.  blocks [16384,20480): K prefix/pad + V^T prefix/pad.
__global__ void prep_kernel(const float* __restrict__ x, const float* __restrict__ pk,
                            const float* __restrict__ pv, unsigned short* __restrict__ xb,
                            unsigned short* __restrict__ Kw, unsigned short* __restrict__ Vt) {
  int bid = blockIdx.x;
  if (bid < 16384) {
    int i = (bid * 256 + threadIdx.x) * 4;
    float4 v = *(const float4*)(x + i);
    ushort4 o;
    o.x = f2bf(v.x); o.y = f2bf(v.y); o.z = f2bf(v.z); o.w = f2bf(v.w);
    *(ushort4*)(xb + i) = o;
  } else {
    int idx = (bid - 16384) * 256 + threadIdx.x;   // 1,048,576
    {  // K: d fastest (coalesced dst + src)
      int d = idx & 63, rr = (idx >> 6) & 63, bh = idx >> 12;
      int row = (rr < P_) ? rr : (1024 + rr);
      float kv = 0.f;
      if (rr < P_) { int b = bh >> 4, h = bh & 15; kv = pk[(b * P_ + rr) * C_ + h * D_ + d]; }
      Kw[((size_t)bh * MP_ + row) * D_ + d] = f2bf(kv);
    }
    {  // V^T: row-slot fastest (coalesced dst; tiny strided src absorbed by L2)
      int mm = idx & 63, d = (idx >> 6) & 63, bh = idx >> 12;
      int row = (mm < P_) ? mm : (1024 + mm);
      float vv = 0.f;
      if (mm < P_) { int b = bh >> 4, h = bh & 15; vv = pv[(b * P_ + mm) * C_ + h * D_ + d]; }
      Vt[((size_t)bh * D_ + d) * MP_ + row] = f2bf(vv);
    }
  }
}

// both weight transposes in one launch: [1024 k][cols n] fp32 -> [n][1024 k] bf16.
// blockIdx.x < 48 -> w_qkv (cols=3072); else w_proj (cols=1024).
__global__ void transpose_cast_kernel(const float* __restrict__ wqkv,
                                      const float* __restrict__ wproj,
                                      unsigned short* __restrict__ oqkv,
                                      unsigned short* __restrict__ oproj) {
  __shared__ unsigned short t[64][68];   // pad 68: breaks bank aliasing on strided read
  int bx = blockIdx.x;
  const float* in;  unsigned short* out;  int cols, n0;
  if (bx < 48) { in = wqkv;  out = oqkv;  cols = 3072; n0 = bx * 64; }
  else         { in = wproj; out = oproj; cols = 1024; n0 = (bx - 48) * 64; }
  int k0 = blockIdx.y * 64;
  int tid = threadIdx.x;
#pragma unroll
  for (int i = 0; i < 16; ++i) {
    int e = i * 256 + tid;
    int kk = e >> 6, nn = e & 63;
    t[kk][nn] = f2bf(in[(size_t)(k0 + kk) * cols + n0 + nn]);
  }
  __syncthreads();
#pragma unroll
  for (int i = 0; i < 16; ++i) {
    int e = i * 256 + tid;
    int nn = e >> 6, kk = e & 63;
    out[(size_t)(n0 + nn) * 1024 + k0 + kk] = t[kk][nn];
  }
}

// ---------------- GEMM: 256x256 tile, BK=64, 8 waves, 8-phase counted-vmcnt pipeline ----
// C[M,Ncols] = A[M,1024] * Bt[Ncols,1024]^T, bf16 in, fp32 acc.
// LDS: [2 dbuf][2 khalf][256 rows][32 k] per operand = 128 KiB total. 16KB "half-tile"
// regions are the staging/consumption quantum. Chunk swizzle byte^=((row>>2)&3)<<4 applied
// to the pre-swizzled per-lane GLOBAL source (global_load_lds dest is linear) and to the
// ds_read address (involution; both-sides rule) -> b128 frag reads are bank-uniform.
// Schedule per K-tile kt (buf=kt&1, nbuf=buf^1): 4 phases; each phase stages ONE half-tile:
//   P0:(kh0,mh0,+Bk0) stage nbuf.A-k1[kt+1] | P1:(kh0,mh1) stage nbuf.B-k1[kt+1], vmcnt(8)
//   P2:(kh1,mh1,+Bk1) stage  buf.A-k0[kt+2] | P3:(kh1,mh0) stage  buf.B-k0[kt+2], vmcnt(8)
// Every stage targets a region whose last reader finished >=1 barrier earlier; vmcnt is
// never drained to 0 in the main loop (epilogue: 8 -> 4 -> 0).
// MODE 0: qkv epilogue (Q^T pre-scaled, Kw, V^T). MODE 1: proj epilogue (+bias, FP32 out).
template <int MODE>
__global__ __launch_bounds__(512, 2) void gemm256(const unsigned short* __restrict__ A,
                                                  const unsigned short* __restrict__ Bt,
                                                  unsigned short* __restrict__ Qt,
                                                  unsigned short* __restrict__ Kw,
                                                  unsigned short* __restrict__ Vt,
                                                  const float* __restrict__ bias,
                                                  float* __restrict__ Out) {
  __shared__ alignas(16) unsigned short As[2][2][8192];   // [dbuf][kh][256r * 32k]
  __shared__ alignas(16) unsigned short Bs[2][2][8192];

  const int tid = threadIdx.x;
  const int w = tid >> 6, lane = tid & 63;
  const int l15 = lane & 15, quad = lane >> 4;
  const int wm = w >> 2, wn = w & 3;            // 2 x 4 wave grid; wave tile 128m x 64n
  const int rt = blockIdx.x, ct = blockIdx.y;

  // swizzled per-lane byte offset for fragment ds_read_b128 (row=l15 within 16-row frag)
  const int lane_off = l15 * 64 + ((quad * 16) ^ ((l15 & 12) << 2));
  const int abase = (wm * 128) * 64;            // wave's A row-block byte base in region
  const int bbase = (wn * 64) * 64;             // wave's B col-block byte base in region

  // staging: wave-uniform LDS slots (1KB each), per-lane inverse-swizzled global source
  const int st0 = (w * 2 + 0) * 512, st1 = (w * 2 + 1) * 512;   // element offsets
  const unsigned short *gA0, *gA1, *gB0, *gB1;
  {
    int phi0 = st0 * 2 + lane * 16;             // physical byte this lane writes (load 0)
    int phi1 = st1 * 2 + lane * 16;
    int lam0 = phi0 ^ (((phi0 >> 8) & 3) << 4); // logical element -> (row, k-chunk)
    int lam1 = phi1 ^ (((phi1 >> 8) & 3) << 4);
    int r0 = lam0 >> 6, k80 = (lam0 >> 4) & 3;
    int r1 = lam1 >> 6, k81 = (lam1 >> 4) & 3;
    gA0 = A + (size_t)(rt * 256 + r0) * 1024 + k80 * 8;
    gA1 = A + (size_t)(rt * 256 + r1) * 1024 + k81 * 8;
    gB0 = Bt + (size_t)(ct * 256 + r0) * 1024 + k80 * 8;
    gB1 = Bt + (size_t)(ct * 256 + r1) * 1024 + k81 * 8;
  }

  f32x4 acc[8][4] = {};
  short8 av[4], bv[4];

#define STAGE_A(BUF, KH, KT)                                                   \
  { async_cp16(&As[BUF][KH][st0], gA0 + (KT) * 64 + (KH) * 32);                \
    async_cp16(&As[BUF][KH][st1], gA1 + (KT) * 64 + (KH) * 32); }
#define STAGE_B(BUF, KH, KT)                                                   \
  { async_cp16(&Bs[BUF][KH][st0], gB0 + (KT) * 64 + (KH) * 32);                \
    async_cp16(&Bs[BUF][KH][st1], gB1 + (KT) * 64 + (KH) * 32); }
#define VMW(CNT) asm volatile("s_waitcnt vmcnt(" #CNT ")" ::: "memory")

  // prologue: ktile0 {A0,B0,A1,B1}, ktile1 {A0,B0}  (12 loads/thread in flight)
  STAGE_A(0, 0, 0); STAGE_B(0, 0, 0);
  STAGE_A(0, 1, 0); STAGE_B(0, 1, 0);
  STAGE_A(1, 0, 1); STAGE_B(1, 0, 1);
  VMW(8);                                       // ktile0 {A0,B0} landed
  __builtin_amdgcn_s_barrier();

#define PHASE(BUF, KH, MH, LOADB, STAGECODE, TAILCODE)                         \
  {                                                                            \
    const char* ab_ = (const char*)&As[BUF][KH][0] + abase + (MH) * 4096;      \
    _Pragma("unroll") for (int mt = 0; mt < 4; ++mt)                           \
        av[mt] = *(const short8*)(ab_ + mt * 1024 + lane_off);                 \
    if (LOADB) {                                                               \
      const char* bb_ = (const char*)&Bs[BUF][KH][0] + bbase;                  \
      _Pragma("unroll") for (int nt = 0; nt < 4; ++nt)                         \
          bv[nt] = *(const short8*)(bb_ + nt * 1024 + lane_off);               \
    }                                                                          \
    STAGECODE;                                                                 \
    __builtin_amdgcn_s_barrier();                                              \
    asm volatile("s_waitcnt lgkmcnt(0)" ::: "memory");                         \
    __builtin_amdgcn_sched_barrier(0);                                         \
    __builtin_amdgcn_s_setprio(1);                                             \
    _Pragma("unroll") for (int mt = 0; mt < 4; ++mt)                           \
      _Pragma("unroll") for (int nt = 0; nt < 4; ++nt)                         \
          acc[(MH) * 4 + mt][nt] = __builtin_amdgcn_mfma_f32_16x16x32_bf16(    \
              av[mt], bv[nt], acc[(MH) * 4 + mt][nt], 0, 0, 0);                \
    __builtin_amdgcn_s_setprio(0);                                             \
    TAILCODE;                                                                  \
    __builtin_amdgcn_s_barrier();                                              \
  }

#define K_ITER(KT, BUF, NBUF, DO01, DO23, VM1C, VM3C)                          \
  {                                                                            \
    PHASE(BUF, 0, 0, true,  { if (DO01) STAGE_A(NBUF, 1, (KT) + 1); }, (void)0); \
    PHASE(BUF, 0, 1, false, { if (DO01) STAGE_B(NBUF, 1, (KT) + 1); }, VM1C);  \
    PHASE(BUF, 1, 1, true,  { if (DO23) STAGE_A(BUF, 0, (KT) + 2); }, (void)0);  \
    PHASE(BUF, 1, 0, false, { if (DO23) STAGE_B(BUF, 0, (KT) + 2); }, VM3C);   \
  }

#pragma unroll 1
  for (int kt = 0; kt < 14; kt += 2) {
    K_ITER(kt, 0, 1, true, true, VMW(8), VMW(8));
    K_ITER(kt + 1, 1, 0, true, true, VMW(8), VMW(8));
  }
  K_ITER(14, 0, 1, true, false, VMW(8), VMW(4));     // last stages: ktile15 {A1,B1}
  K_ITER(15, 1, 0, false, false, VMW(0), (void)0);   // final drain

#undef K_ITER
#undef PHASE
#undef VMW
#undef STAGE_B
#undef STAGE_A

  // epilogue: C/D layout col = l15 (B side), row = quad*4 + r (A side)
  if (MODE == 0) {
    const int b = rt >> 2;                       // 256-row tiles align with batches
    const int colg = ct * 4 + wn;                // global 64-col group, 0..47
    const int sel = colg >> 4;                   // 0=Q, 1=K, 2=V
    const int h = colg & 15;
    const int bh = b * 16 + h;
    const int nbase = (rt & 3) * 256 + wm * 128 + quad * 4;   // row within batch
#pragma unroll
    for (int nf = 0; nf < 4; ++nf) {
      const int d = nf * 16 + l15;
#pragma unroll
      for (int rf = 0; rf < 8; ++rf) {
        const int n0 = nbase + rf * 16;
        if (sel == 1) {
          // K: [bh][m][d] layout, lane holds fixed d for 4 consecutive n -> scalar stores
#pragma unroll
          for (int r = 0; r < 4; ++r)
            Kw[((size_t)bh * MP_ + P_ + n0 + r) * D_ + d] = f2bf(acc[rf][nf][r]);
        } else if (sel == 0) {
          ushort4 p4;                            // softmax scale folded into Q
          p4.x = f2bf(acc[rf][nf][0] * 0.125f);
          p4.y = f2bf(acc[rf][nf][1] * 0.125f);
          p4.z = f2bf(acc[rf][nf][2] * 0.125f);
          p4.w = f2bf(acc[rf][nf][3] * 0.125f);
          *(ushort4*)&Qt[((size_t)bh * D_ + d) * N_ + n0] = p4;
        } else {
          ushort4 p4;
          p4.x = f2bf(acc[rf][nf][0]);
          p4.y = f2bf(acc[rf][nf][1]);
          p4.z = f2bf(acc[rf][nf][2]);
          p4.w = f2bf(acc[rf][nf][3]);
          *(ushort4*)&Vt[((size_t)bh * D_ + d) * MP_ + P_ + n0] = p4;
        }
      }
    }
  } else {
#pragma unroll
    for (int nf = 0; nf < 4; ++nf) {
      const int col = ct * 256 + wn * 64 + nf * 16 + l15;
      const float bs = bias[col];
#pragma unroll
      for (int rf = 0; rf < 8; ++rf) {
#pragma unroll
        for (int r = 0; r < 4; ++r) {
          const int row = rt * 256 + wm * 128 + rf * 16 + quad * 4 + r;
          Out[(size_t)row * C_ + col] = acc[rf][nf][r] + bs;   // d_out is FP32
        }
      }
    }
  }
}

// ---------------- attention ----------------
// grid (8 q-tiles, 256 bh), block 256 = 4 waves x 32 q-rows (128 q-rows/block).
// K/V chunks in split-panel LDS layout (64B rows -> conflict-free b128 reads).
// Ps stride 80 (160B, 16B-aligned, bank-spread). Q read from Q^T via per-block gather.
__global__ __launch_bounds__(256) void attn_kernel(const unsigned short* __restrict__ Qt,
                                                   const unsigned short* __restrict__ Kw,
                                                   const unsigned short* __restrict__ Vt,
                                                   unsigned short* __restrict__ Ao) {
  __shared__ unsigned short Ks[4096];      // 2 panels [64 m][32 d]
  __shared__ unsigned short Vs[4096];      // 2 panels [64 d][32 m]
  __shared__ unsigned short Ps[4][32 * 80];
  const int tid = threadIdx.x;
  const int w = tid >> 6, lane = tid & 63;
  const int l15 = lane & 15, quad = lane >> 4, q8 = quad * 8;
  const int qt = blockIdx.x, bh = blockIdx.y;

  // Q A-frags from Q^T[bh][d][n]: elem j of half h = Q[qrow][h*32 + q8 + j]
  short8 aq[2][2];
#pragma unroll
  for (int mq = 0; mq < 2; ++mq) {
    int qrow = qt * 128 + w * 32 + mq * 16 + l15;
    const unsigned short* Qb = Qt + (size_t)bh * D_ * N_ + qrow;
#pragma unroll
    for (int h = 0; h < 2; ++h)
#pragma unroll
      for (int j = 0; j < 8; ++j)
        aq[mq][h][j] = (short)Qb[(size_t)(h * 32 + q8 + j) * N_];
  }

  f32x4 oacc[2][4] = {};
  float den[2][4] = {};

  const unsigned short* Kbh = Kw + (size_t)bh * MP_ * 64;
  const unsigned short* Vbh = Vt + (size_t)bh * 64 * MP_;

  for (int ch = 0; ch < 17; ++ch) {
    __syncthreads();
#pragma unroll
    for (int r = 0; r < 2; ++r) {
      int c = r * 256 + tid;
      int p = c >> 8, mrow = (c >> 2) & 63, s = c & 3;   // chunk -> (panel, row, 16B seg)
      async_cp16(&Ks[(r * 256 + (w << 6)) * 8], Kbh + (size_t)(ch * 64 + mrow) * 64 + p * 32 + s * 8);
      async_cp16(&Vs[(r * 256 + (w << 6)) * 8], Vbh + (size_t)mrow * MP_ + ch * 64 + p * 32 + s * 8);
    }
    __syncthreads();

    unsigned short* Pw = &Ps[w][0];
#pragma unroll
    for (int ct2 = 0; ct2 < 4; ++ct2) {
      short8 b0 = *(const short8*)&Ks[(ct2 * 16 + l15) * 32 + q8];         // d 0..31
      short8 b1 = *(const short8*)&Ks[2048 + (ct2 * 16 + l15) * 32 + q8];  // d 32..63
      int mg = ch * 64 + ct2 * 16 + l15;
      bool valid = (mg < M_);
#pragma unroll
      for (int mq = 0; mq < 2; ++mq) {
        f32x4 s = {};
        s = __builtin_amdgcn_mfma_f32_16x16x32_bf16(aq[mq][0], b0, s, 0, 0, 0);
        s = __builtin_amdgcn_mfma_f32_16x16x32_bf16(aq[mq][1], b1, s, 0, 0, 0);
#pragma unroll
        for (int r = 0; r < 4; ++r) {
          float p = valid ? __expf(s[r]) : 0.f;
          den[mq][r] += p;
          Pw[(mq * 16 + quad * 4 + r) * 80 + ct2 * 16 + l15] = f2bf(p);
        }
      }
    }

    short8 ap[2][2];
#pragma unroll
    for (int mq = 0; mq < 2; ++mq) {
      ap[mq][0] = *(const short8*)&Pw[(mq * 16 + l15) * 80 + q8];
      ap[mq][1] = *(const short8*)&Pw[(mq * 16 + l15) * 80 + 32 + q8];
    }
#pragma unroll
    for (int dt = 0; dt < 4; ++dt) {
      short8 b0 = *(const short8*)&Vs[(dt * 16 + l15) * 32 + q8];          // m 0..31
      short8 b1 = *(const short8*)&Vs[2048 + (dt * 16 + l15) * 32 + q8];   // m 32..63
#pragma unroll
      for (int mq = 0; mq < 2; ++mq) {
        oacc[mq][dt] = __builtin_amdgcn_mfma_f32_16x16x32_bf16(ap[mq][0], b0, oacc[mq][dt], 0, 0, 0);
        oacc[mq][dt] = __builtin_amdgcn_mfma_f32_16x16x32_bf16(ap[mq][1], b1, oacc[mq][dt], 0, 0, 0);
      }
    }
  }

  // reduce denominator across the 16 lanes sharing each q-row
#pragma unroll
  for (int mq = 0; mq < 2; ++mq)
#pragma unroll
    for (int r = 0; r < 4; ++r) {
      float d2 = den[mq][r];
      d2 += __shfl_xor(d2, 1);
      d2 += __shfl_xor(d2, 2);
      d2 += __shfl_xor(d2, 4);
      d2 += __shfl_xor(d2, 8);
      den[mq][r] = 1.f / d2;
    }

  int b = bh >> 4, h = bh & 15;
#pragma unroll
  for (int mq = 0; mq < 2; ++mq)
#pragma unroll
    for (int dt = 0; dt < 4; ++dt)
#pragma unroll
      for (int r = 0; r < 4; ++r) {
        int qrow = qt * 128 + w * 32 + mq * 16 + quad * 4 + r;
        size_t dst = ((size_t)(b * N_ + qrow)) * C_ + h * 64 + dt * 16 + l15;
        Ao[dst] = f2bf(oacc[mq][dt][r] * den[mq][r]);
      }
}

// ---------------- launch ----------------

extern "C" void kernel_launch(void* const* d_in, const int* in_sizes, int n_in,
                              void* d_out, int out_size, void* d_ws, size_t ws_size,
                              hipStream_t stream) {
  const float* x      = (const float*)d_in[0];
  const float* pk     = (const float*)d_in[1];
  const float* pv     = (const float*)d_in[2];
  const float* w_qkv  = (const float*)d_in[3];
  const float* w_proj = (const float*)d_in[4];
  const float* b_proj = (const float*)d_in[5];

  char* ws = (char*)d_ws;
  unsigned short* xb     = (unsigned short*)(ws);                 // 33,554,432 B
  unsigned short* wqkvT  = (unsigned short*)(ws + 33554432);      //  6,291,456 B
  unsigned short* wprojT = (unsigned short*)(ws + 39845888);      //  2,097,152 B
  unsigned short* Qt     = (unsigned short*)(ws + 41943040);      // 33,554,432 B
  unsigned short* Kw     = (unsigned short*)(ws + 75497472);      // 35,651,584 B
  unsigned short* Vt     = (unsigned short*)(ws + 111149056);     // 35,651,584 B
  unsigned short* attn   = xb;  // alias: xb is dead after the QKV GEMM

  prep_kernel<<<20480, 256, 0, stream>>>(x, pk, pv, xb, Kw, Vt);
  transpose_cast_kernel<<<dim3(64, 16), 256, 0, stream>>>(w_qkv, w_proj, wqkvT, wprojT);

  gemm256<0><<<dim3(64, 12), 512, 0, stream>>>(xb, wqkvT, Qt, Kw, Vt, nullptr, nullptr);
  attn_kernel<<<dim3(8, 256), 256, 0, stream>>>(Qt, Kw, Vt, attn);
  gemm256<1><<<dim3(64, 4), 512, 0, stream>>>(attn, wprojT, nullptr, nullptr, nullptr,
                                              b_proj, (float*)d_out);
}

// Round 2
// 407.381 us; speedup vs baseline: 1.0817x; 1.0400x over previous
//
#include <hip/hip_runtime.h>
#include <stdint.h>

// Problem constants
#define B_  16
#define N_  1024
#define C_  1024
#define H_  16
#define D_  64
#define P_  16
#define M_  1040           // P + N
#define MP_ 1088           // M padded to 17*64

typedef __attribute__((ext_vector_type(8))) short short8;   // 8 bf16 = 4 VGPRs
typedef __attribute__((ext_vector_type(4))) float f32x4;    // MFMA C/D frag

__device__ __forceinline__ unsigned short f2bf(float f) {
  unsigned int u = __float_as_uint(f);
  u += 0x7fffu + ((u >> 16) & 1u);          // RNE
  return (unsigned short)(u >> 16);
}

// async global->LDS, 16B per lane. LDS dest must be wave-uniform base (+lane*16 implicit).
__device__ __forceinline__ void async_cp16(void* lds, const void* g) {
  __builtin_amdgcn_global_load_lds(
      (__attribute__((address_space(1))) void*)(void*)g,
      (__attribute__((address_space(3))) void*)lds,
      16, 0, 0);
}

// ---------------- prep kernels (merged: 2 launches) ----------------

// blocks [0,16384): x fp32->bf16 cast.  blocks [16384,20480): K prefix/pad + V^T prefix/pad.
__global__ void prep_kernel(const float* __restrict__ x, const float* __restrict__ pk,
                            const float* __restrict__ pv, unsigned short* __restrict__ xb,
                            unsigned short* __restrict__ Kw, unsigned short* __restrict__ Vt) {
  int bid = blockIdx.x;
  if (bid < 16384) {
    int i = (bid * 256 + threadIdx.x) * 4;
    float4 v = *(const float4*)(x + i);
    ushort4 o;
    o.x = f2bf(v.x); o.y = f2bf(v.y); o.z = f2bf(v.z); o.w = f2bf(v.w);
    *(ushort4*)(xb + i) = o;
  } else {
    int idx = (bid - 16384) * 256 + threadIdx.x;   // 1,048,576
    {  // K: d fastest (coalesced dst + src)
      int d = idx & 63, rr = (idx >> 6) & 63, bh = idx >> 12;
      int row = (rr < P_) ? rr : (1024 + rr);
      float kv = 0.f;
      if (rr < P_) { int b = bh >> 4, h = bh & 15; kv = pk[(b * P_ + rr) * C_ + h * D_ + d]; }
      Kw[((size_t)bh * MP_ + row) * D_ + d] = f2bf(kv);
    }
    {  // V^T: row-slot fastest (coalesced dst; tiny strided src absorbed by L2)
      int mm = idx & 63, d = (idx >> 6) & 63, bh = idx >> 12;
      int row = (mm < P_) ? mm : (1024 + mm);
      float vv = 0.f;
      if (mm < P_) { int b = bh >> 4, h = bh & 15; vv = pv[(b * P_ + mm) * C_ + h * D_ + d]; }
      Vt[((size_t)bh * D_ + d) * MP_ + row] = f2bf(vv);
    }
  }
}

// both weight transposes in one launch: [1024 k][cols n] fp32 -> [n][1024 k] bf16.
// blockIdx.x < 48 -> w_qkv (cols=3072); else w_proj (cols=1024).
__global__ void transpose_cast_kernel(const float* __restrict__ wqkv,
                                      const float* __restrict__ wproj,
                                      unsigned short* __restrict__ oqkv,
                                      unsigned short* __restrict__ oproj) {
  __shared__ unsigned short t[64][68];   // pad 68: breaks bank aliasing on strided read
  int bx = blockIdx.x;
  const float* in;  unsigned short* out;  int cols, n0;
  if (bx < 48) { in = wqkv;  out = oqkv;  cols = 3072; n0 = bx * 64; }
  else         { in = wproj; out = oproj; cols = 1024; n0 = (bx - 48) * 64; }
  int k0 = blockIdx.y * 64;
  int tid = threadIdx.x;
#pragma unroll
  for (int i = 0; i < 16; ++i) {
    int e = i * 256 + tid;
    int kk = e >> 6, nn = e & 63;
    t[kk][nn] = f2bf(in[(size_t)(k0 + kk) * cols + n0 + nn]);
  }
  __syncthreads();
#pragma unroll
  for (int i = 0; i < 16; ++i) {
    int e = i * 256 + tid;
    int nn = e >> 6, kk = e & 63;
    out[(size_t)(n0 + nn) * 1024 + k0 + kk] = t[kk][nn];
  }
}

// ---------------- GEMM: 256x256 tile, BK=32, 8 waves, counted-lgkmcnt overlap ---------
// C[M,Ncols] = A[M,1024] * Bt[Ncols,1024]^T, bf16 in, fp32 acc.
// LDS: S[4 buf][A|B][256 rows x 32 k] = 128 KiB. Staging runs 2 K-tiles ahead
// (buffer kt+2 holds tile kt-2, whose reads complete before barrier kt-1: safe).
// ONE barrier per K-tile. Per tile (buf = kt&3, reg set toggles X/Y per tile):
//   RD g1(kt)[4 ds] ; STAGE(kt+2)[4 vm] ; lgkmcnt(4) ; MFMA g0 x16
//   vmcnt(4)[kt+1 landed, never 0 mid-loop] ; s_barrier
//   RD g0(kt+1)[8 ds, other set] ; lgkmcnt(8) ; MFMA g1 x16
// MFMA g0 overlaps LDS processing of g1 reads + stage issues; MFMA g1 overlaps the
// next tile's g0 reads -> LDS pipe and MFMA pipe run concurrently instead of
// alternating (round-1 failure mode: barrier+lgkmcnt(0) per phase serialized them).
// LDS swizzle: 16B-chunk col p = c ^ ((row>>1)&3); reads use the same XOR; staging
// applies the inverse on the per-lane GLOBAL source (global_load_lds dest linear).
// Per 16-lane group each 4-bank cluster is hit exactly 2x (the b128 floor).
// MODE 0: qkv epilogue (Q^T pre-scaled, Kw, V^T). MODE 1: proj epilogue (+bias, FP32 out).
template <int MODE>
__global__ __launch_bounds__(512, 2) void gemm256(const unsigned short* __restrict__ A,
                                                  const unsigned short* __restrict__ Bt,
                                                  unsigned short* __restrict__ Qt,
                                                  unsigned short* __restrict__ Kw,
                                                  unsigned short* __restrict__ Vt,
                                                  const float* __restrict__ bias,
                                                  float* __restrict__ Out) {
  __shared__ alignas(16) unsigned short S[4][2][8192];   // [buf][A|B][256r * 32k]

  const int tid = threadIdx.x;
  const int w = tid >> 6, lane = tid & 63;
  const int l15 = lane & 15, quad = lane >> 4;
  const int wm = w >> 2, wn = w & 3;            // 2 x 4 wave grid; wave tile 128m x 64n
  const int rt = blockIdx.x, ct = blockIdx.y;

  // fragment ds_read_b128 byte offset: row l15 (64B rows), k-chunk quad, chunk-swizzled
  const int lane_off = l15 * 64 + ((quad * 16) ^ ((l15 & 6) << 3));
  const int abase = wm * 8192;                  // wave's A row-block byte base (128 rows)
  const int bbase = wn * 4096;                  // wave's B col-block byte base (64 rows)

  // staging: wave w fills 1KB slots {2w, 2w+1} of each 16KB panel; per-lane source is
  // inverse-swizzled: lane i -> row lr = i>>2 (of 16-row slot), k-chunk (i&3)^((i>>3)&3)
  const int s0 = w * 2, s1 = s0 + 1;
  const int lr = lane >> 2;
  const int lc = (lane & 3) ^ ((lane >> 3) & 3);
  const unsigned short* gA0 = A + (size_t)(rt * 256 + s0 * 16 + lr) * 1024 + lc * 8;
  const unsigned short* gA1 = A + (size_t)(rt * 256 + s1 * 16 + lr) * 1024 + lc * 8;
  const unsigned short* gB0 = Bt + (size_t)(ct * 256 + s0 * 16 + lr) * 1024 + lc * 8;
  const unsigned short* gB1 = Bt + (size_t)(ct * 256 + s1 * 16 + lr) * 1024 + lc * 8;

  f32x4 acc[8][4] = {};
  short8 avX[4], bvX[4], avY[4], bvY[4], aw[4];

#define STAGE(KT) {                                                            \
    unsigned short* ls = &S[(KT) & 3][0][0];                                   \
    async_cp16(ls + s0 * 512, gA0 + (KT) * 32);                                \
    async_cp16(ls + s1 * 512, gA1 + (KT) * 32);                                \
    async_cp16(ls + 8192 + s0 * 512, gB0 + (KT) * 32);                         \
    async_cp16(ls + 8192 + s1 * 512, gB1 + (KT) * 32); }

#define RD_G0(KT, av, bv) {                                                    \
    const char* pa_ = (const char*)&S[(KT) & 3][0][0] + abase;                 \
    const char* pb_ = (const char*)&S[(KT) & 3][1][0] + bbase;                 \
    _Pragma("unroll") for (int mt = 0; mt < 4; ++mt)                           \
        av[mt] = *(const short8*)(pa_ + mt * 1024 + lane_off);                 \
    _Pragma("unroll") for (int nt = 0; nt < 4; ++nt)                           \
        bv[nt] = *(const short8*)(pb_ + nt * 1024 + lane_off); }

#define RD_G1(KT) {                                                            \
    const char* pa_ = (const char*)&S[(KT) & 3][0][0] + abase + 4096;          \
    _Pragma("unroll") for (int mt = 0; mt < 4; ++mt)                           \
        aw[mt] = *(const short8*)(pa_ + mt * 1024 + lane_off); }

#define MM_G0(av, bv)                                                          \
  __builtin_amdgcn_s_setprio(1);                                               \
  _Pragma("unroll") for (int mt = 0; mt < 4; ++mt)                             \
    _Pragma("unroll") for (int nt = 0; nt < 4; ++nt)                           \
        acc[mt][nt] = __builtin_amdgcn_mfma_f32_16x16x32_bf16(av[mt], bv[nt],  \
                                                              acc[mt][nt], 0, 0, 0); \
  __builtin_amdgcn_s_setprio(0);

#define MM_G1(bv)                                                              \
  __builtin_amdgcn_s_setprio(1);                                               \
  _Pragma("unroll") for (int mt = 0; mt < 4; ++mt)                             \
    _Pragma("unroll") for (int nt = 0; nt < 4; ++nt)                           \
        acc[4 + mt][nt] = __builtin_amdgcn_mfma_f32_16x16x32_bf16(aw[mt], bv[nt], \
                                                                  acc[4 + mt][nt], 0, 0, 0); \
  __builtin_amdgcn_s_setprio(0);

#define LGKM(N) do { asm volatile("s_waitcnt lgkmcnt(" #N ")" ::: "memory");   \
                     __builtin_amdgcn_sched_barrier(0); } while (0)
#define VMC(N)  asm volatile("s_waitcnt vmcnt(" #N ")" ::: "memory")

#define TILE(KT, avC, bvC, avN, bvN) {                                         \
    RD_G1(KT);                     /* 4 ds: g1 A-frags                     */  \
    STAGE((KT) + 2);               /* 4 vm: 2 tiles ahead                  */  \
    LGKM(4);                       /* g0(KT) regs ready (12 -> 4 pending)  */  \
    MM_G0(avC, bvC);                                                           \
    __builtin_amdgcn_sched_barrier(0);                                         \
    VMC(4);                        /* KT+1's 4 loads landed (8 in flight)  */  \
    __builtin_amdgcn_s_barrier();  /* buf[KT+1] visible                    */  \
    RD_G0((KT) + 1, avN, bvN);     /* 8 ds into other reg set              */  \
    LGKM(8);                       /* g1(KT) regs ready                    */  \
    MM_G1(bvC);                                                                \
  }

  // prologue: stage tiles 0,1; make tile 0 visible; preload its g0 frags
  STAGE(0); STAGE(1);
  VMC(4);
  __builtin_amdgcn_s_barrier();
  RD_G0(0, avX, bvX);

#pragma unroll 1
  for (int kt = 0; kt < 30; kt += 2) {
    TILE(kt, avX, bvX, avY, bvY);
    TILE(kt + 1, avY, bvY, avX, bvX);
  }
  // kt = 30: no staging left; must fully drain vmcnt for tile 31
  RD_G1(30);
  LGKM(4);
  MM_G0(avX, bvX);
  __builtin_amdgcn_sched_barrier(0);
  VMC(0);
  __builtin_amdgcn_s_barrier();
  RD_G0(31, avY, bvY);
  LGKM(8);
  MM_G1(bvX);
  // kt = 31
  RD_G1(31);
  LGKM(4);
  MM_G0(avY, bvY);
  LGKM(0);
  __builtin_amdgcn_sched_barrier(0);
  MM_G1(bvY);

#undef TILE
#undef VMC
#undef LGKM
#undef MM_G1
#undef MM_G0
#undef RD_G1
#undef RD_G0
#undef STAGE

  // epilogue: C/D layout col = l15 (B side), row = quad*4 + r (A side)
  if (MODE == 0) {
    const int b = rt >> 2;                       // 256-row tiles align with batches
    const int colg = ct * 4 + wn;                // global 64-col group, 0..47
    const int sel = colg >> 4;                   // 0=Q, 1=K, 2=V
    const int h = colg & 15;
    const int bh = b * 16 + h;
    const int nbase = (rt & 3) * 256 + wm * 128 + quad * 4;   // row within batch
#pragma unroll
    for (int nf = 0; nf < 4; ++nf) {
      const int d = nf * 16 + l15;
#pragma unroll
      for (int rf = 0; rf < 8; ++rf) {
        const int n0 = nbase + rf * 16;
        if (sel == 1) {
          // K: [bh][m][d] layout, lane holds fixed d for 4 consecutive n -> scalar stores
#pragma unroll
          for (int r = 0; r < 4; ++r)
            Kw[((size_t)bh * MP_ + P_ + n0 + r) * D_ + d] = f2bf(acc[rf][nf][r]);
        } else if (sel == 0) {
          ushort4 p4;                            // softmax scale folded into Q
          p4.x = f2bf(acc[rf][nf][0] * 0.125f);
          p4.y = f2bf(acc[rf][nf][1] * 0.125f);
          p4.z = f2bf(acc[rf][nf][2] * 0.125f);
          p4.w = f2bf(acc[rf][nf][3] * 0.125f);
          *(ushort4*)&Qt[((size_t)bh * D_ + d) * N_ + n0] = p4;
        } else {
          ushort4 p4;
          p4.x = f2bf(acc[rf][nf][0]);
          p4.y = f2bf(acc[rf][nf][1]);
          p4.z = f2bf(acc[rf][nf][2]);
          p4.w = f2bf(acc[rf][nf][3]);
          *(ushort4*)&Vt[((size_t)bh * D_ + d) * MP_ + P_ + n0] = p4;
        }
      }
    }
  } else {
#pragma unroll
    for (int nf = 0; nf < 4; ++nf) {
      const int col = ct * 256 + wn * 64 + nf * 16 + l15;
      const float bs = bias[col];
#pragma unroll
      for (int rf = 0; rf < 8; ++rf) {
#pragma unroll
        for (int r = 0; r < 4; ++r) {
          const int row = rt * 256 + wm * 128 + rf * 16 + quad * 4 + r;
          Out[(size_t)row * C_ + col] = acc[rf][nf][r] + bs;   // d_out is FP32
        }
      }
    }
  }
}

// ---------------- attention ----------------
// grid (8 q-tiles, 256 bh), block 256 = 4 waves x 32 q-rows (128 q-rows/block).
// K/V chunks in split-panel LDS layout (64B rows -> conflict-free b128 reads).
// Ps stride 80 (160B, 16B-aligned, bank-spread). Q read from Q^T via per-block gather.
__global__ __launch_bounds__(256) void attn_kernel(const unsigned short* __restrict__ Qt,
                                                   const unsigned short* __restrict__ Kw,
                                                   const unsigned short* __restrict__ Vt,
                                                   unsigned short* __restrict__ Ao) {
  __shared__ unsigned short Ks[4096];      // 2 panels [64 m][32 d]
  __shared__ unsigned short Vs[4096];      // 2 panels [64 d][32 m]
  __shared__ unsigned short Ps[4][32 * 80];
  const int tid = threadIdx.x;
  const int w = tid >> 6, lane = tid & 63;
  const int l15 = lane & 15, quad = lane >> 4, q8 = quad * 8;
  const int qt = blockIdx.x, bh = blockIdx.y;

  // Q A-frags from Q^T[bh][d][n]: elem j of half h = Q[qrow][h*32 + q8 + j]
  short8 aq[2][2];
#pragma unroll
  for (int mq = 0; mq < 2; ++mq) {
    int qrow = qt * 128 + w * 32 + mq * 16 + l15;
    const unsigned short* Qb = Qt + (size_t)bh * D_ * N_ + qrow;
#pragma unroll
    for (int h = 0; h < 2; ++h)
#pragma unroll
      for (int j = 0; j < 8; ++j)
        aq[mq][h][j] = (short)Qb[(size_t)(h * 32 + q8 + j) * N_];
  }

  f32x4 oacc[2][4] = {};
  float den[2][4] = {};

  const unsigned short* Kbh = Kw + (size_t)bh * MP_ * 64;
  const unsigned short* Vbh = Vt + (size_t)bh * 64 * MP_;

  for (int ch = 0; ch < 17; ++ch) {
    __syncthreads();
#pragma unroll
    for (int r = 0; r < 2; ++r) {
      int c = r * 256 + tid;
      int p = c >> 8, mrow = (c >> 2) & 63, s = c & 3;   // chunk -> (panel, row, 16B seg)
      async_cp16(&Ks[(r * 256 + (w << 6)) * 8], Kbh + (size_t)(ch * 64 + mrow) * 64 + p * 32 + s * 8);
      async_cp16(&Vs[(r * 256 + (w << 6)) * 8], Vbh + (size_t)mrow * MP_ + ch * 64 + p * 32 + s * 8);
    }
    __syncthreads();

    unsigned short* Pw = &Ps[w][0];
#pragma unroll
    for (int ct2 = 0; ct2 < 4; ++ct2) {
      short8 b0 = *(const short8*)&Ks[(ct2 * 16 + l15) * 32 + q8];         // d 0..31
      short8 b1 = *(const short8*)&Ks[2048 + (ct2 * 16 + l15) * 32 + q8];  // d 32..63
      int mg = ch * 64 + ct2 * 16 + l15;
      bool valid = (mg < M_);
#pragma unroll
      for (int mq = 0; mq < 2; ++mq) {
        f32x4 s = {};
        s = __builtin_amdgcn_mfma_f32_16x16x32_bf16(aq[mq][0], b0, s, 0, 0, 0);
        s = __builtin_amdgcn_mfma_f32_16x16x32_bf16(aq[mq][1], b1, s, 0, 0, 0);
#pragma unroll
        for (int r = 0; r < 4; ++r) {
          float p = valid ? __expf(s[r]) : 0.f;
          den[mq][r] += p;
          Pw[(mq * 16 + quad * 4 + r) * 80 + ct2 * 16 + l15] = f2bf(p);
        }
      }
    }

    short8 ap[2][2];
#pragma unroll
    for (int mq = 0; mq < 2; ++mq) {
      ap[mq][0] = *(const short8*)&Pw[(mq * 16 + l15) * 80 + q8];
      ap[mq][1] = *(const short8*)&Pw[(mq * 16 + l15) * 80 + 32 + q8];
    }
#pragma unroll
    for (int dt = 0; dt < 4; ++dt) {
      short8 b0 = *(const short8*)&Vs[(dt * 16 + l15) * 32 + q8];          // m 0..31
      short8 b1 = *(const short8*)&Vs[2048 + (dt * 16 + l15) * 32 + q8];   // m 32..63
#pragma unroll
      for (int mq = 0; mq < 2; ++mq) {
        oacc[mq][dt] = __builtin_amdgcn_mfma_f32_16x16x32_bf16(ap[mq][0], b0, oacc[mq][dt], 0, 0, 0);
        oacc[mq][dt] = __builtin_amdgcn_mfma_f32_16x16x32_bf16(ap[mq][1], b1, oacc[mq][dt], 0, 0, 0);
      }
    }
  }

  // reduce denominator across the 16 lanes sharing each q-row
#pragma unroll
  for (int mq = 0; mq < 2; ++mq)
#pragma unroll
    for (int r = 0; r < 4; ++r) {
      float d2 = den[mq][r];
      d2 += __shfl_xor(d2, 1);
      d2 += __shfl_xor(d2, 2);
      d2 += __shfl_xor(d2, 4);
      d2 += __shfl_xor(d2, 8);
      den[mq][r] = 1.f / d2;
    }

  int b = bh >> 4, h = bh & 15;
#pragma unroll
  for (int mq = 0; mq < 2; ++mq)
#pragma unroll
    for (int dt = 0; dt < 4; ++dt)
#pragma unroll
      for (int r = 0; r < 4; ++r) {
        int qrow = qt * 128 + w * 32 + mq * 16 + quad * 4 + r;
        size_t dst = ((size_t)(b * N_ + qrow)) * C_ + h * 64 + dt * 16 + l15;
        Ao[dst] = f2bf(oacc[mq][dt][r] * den[mq][r]);
      }
}

// ---------------- launch ----------------

extern "C" void kernel_launch(void* const* d_in, const int* in_sizes, int n_in,
                              void* d_out, int out_size, void* d_ws, size_t ws_size,
                              hipStream_t stream) {
  const float* x      = (const float*)d_in[0];
  const float* pk     = (const float*)d_in[1];
  const float* pv     = (const float*)d_in[2];
  const float* w_qkv  = (const float*)d_in[3];
  const float* w_proj = (const float*)d_in[4];
  const float* b_proj = (const float*)d_in[5];

  char* ws = (char*)d_ws;
  unsigned short* xb     = (unsigned short*)(ws);                 // 33,554,432 B
  unsigned short* wqkvT  = (unsigned short*)(ws + 33554432);      //  6,291,456 B
  unsigned short* wprojT = (unsigned short*)(ws + 39845888);      //  2,097,152 B
  unsigned short* Qt     = (unsigned short*)(ws + 41943040);      // 33,554,432 B
  unsigned short* Kw     = (unsigned short*)(ws + 75497472);      // 35,651,584 B
  unsigned short* Vt     = (unsigned short*)(ws + 111149056);     // 35,651,584 B
  unsigned short* attn   = xb;  // alias: xb is dead after the QKV GEMM

  prep_kernel<<<20480, 256, 0, stream>>>(x, pk, pv, xb, Kw, Vt);
  transpose_cast_kernel<<<dim3(64, 16), 256, 0, stream>>>(w_qkv, w_proj, wqkvT, wprojT);

  gemm256<0><<<dim3(64, 12), 512, 0, stream>>>(xb, wqkvT, Qt, Kw, Vt, nullptr, nullptr);
  attn_kernel<<<dim3(8, 256), 256, 0, stream>>>(Qt, Kw, Vt, attn);
  gemm256<1><<<dim3(64, 4), 512, 0, stream>>>(attn, wprojT, nullptr, nullptr, nullptr,
                                              b_proj, (float*)d_out);
}

// Round 5
// 405.973 us; speedup vs baseline: 1.0855x; 1.0035x over previous
//
#include <hip/hip_runtime.h>
#include <stdint.h>

// Problem constants
#define B_  16
#define N_  1024
#define C_  1024
#define H_  16
#define D_  64
#define P_  16
#define M_  1040           // P + N
#define MP_ 1088           // M padded to 17*64

typedef __attribute__((ext_vector_type(8))) short short8;   // 8 bf16 = 4 VGPRs
typedef __attribute__((ext_vector_type(4))) float f32x4;    // MFMA C/D frag

__device__ __forceinline__ unsigned short f2bf(float f) {
  unsigned int u = __float_as_uint(f);
  u += 0x7fffu + ((u >> 16) & 1u);          // RNE
  return (unsigned short)(u >> 16);
}

__device__ __forceinline__ unsigned int cvt_pk_bf16(float lo, float hi) {
  unsigned int r;
  asm("v_cvt_pk_bf16_f32 %0, %1, %2" : "=v"(r) : "v"(lo), "v"(hi));
  return r;
}

// 2^x via the HW transcendental unit (v_exp_f32 IS exp2 on gfx9xx).
__device__ __forceinline__ float exp2_hw(float x) {
  float r;
  asm("v_exp_f32 %0, %1" : "=v"(r) : "v"(x));
  return r;
}

// async global->LDS, 16B per lane. LDS dest must be wave-uniform base (+lane*16 implicit).
__device__ __forceinline__ void async_cp16(void* lds, const void* g) {
  __builtin_amdgcn_global_load_lds(
      (__attribute__((address_space(1))) void*)(void*)g,
      (__attribute__((address_space(3))) void*)lds,
      16, 0, 0);
}

// ---------------- prep kernels (merged: 2 launches) ----------------

// blocks [0,16384): x fp32->bf16 cast.  blocks [16384,20480): K prefix/pad + V^T prefix/pad.
__global__ void prep_kernel(const float* __restrict__ x, const float* __restrict__ pk,
                            const float* __restrict__ pv, unsigned short* __restrict__ xb,
                            unsigned short* __restrict__ Kw, unsigned short* __restrict__ Vt) {
  int bid = blockIdx.x;
  if (bid < 16384) {
    int i = (bid * 256 + threadIdx.x) * 4;
    float4 v = *(const float4*)(x + i);
    ushort4 o;
    o.x = f2bf(v.x); o.y = f2bf(v.y); o.z = f2bf(v.z); o.w = f2bf(v.w);
    *(ushort4*)(xb + i) = o;
  } else {
    int idx = (bid - 16384) * 256 + threadIdx.x;   // 1,048,576
    {  // K: d fastest (coalesced dst + src)
      int d = idx & 63, rr = (idx >> 6) & 63, bh = idx >> 12;
      int row = (rr < P_) ? rr : (1024 + rr);
      float kv = 0.f;
      if (rr < P_) { int b = bh >> 4, h = bh & 15; kv = pk[(b * P_ + rr) * C_ + h * D_ + d]; }
      Kw[((size_t)bh * MP_ + row) * D_ + d] = f2bf(kv);
    }
    {  // V^T: row-slot fastest (coalesced dst; tiny strided src absorbed by L2)
      int mm = idx & 63, d = (idx >> 6) & 63, bh = idx >> 12;
      int row = (mm < P_) ? mm : (1024 + mm);
      float vv = 0.f;
      if (mm < P_) { int b = bh >> 4, h = bh & 15; vv = pv[(b * P_ + mm) * C_ + h * D_ + d]; }
      Vt[((size_t)bh * D_ + d) * MP_ + row] = f2bf(vv);
    }
  }
}

// both weight transposes in one launch: [1024 k][cols n] fp32 -> [n][1024 k] bf16.
// blockIdx.x < 48 -> w_qkv (cols=3072); else w_proj (cols=1024).
__global__ void transpose_cast_kernel(const float* __restrict__ wqkv,
                                      const float* __restrict__ wproj,
                                      unsigned short* __restrict__ oqkv,
                                      unsigned short* __restrict__ oproj) {
  __shared__ unsigned short t[64][68];   // pad 68: breaks bank aliasing on strided read
  int bx = blockIdx.x;
  const float* in;  unsigned short* out;  int cols, n0;
  if (bx < 48) { in = wqkv;  out = oqkv;  cols = 3072; n0 = bx * 64; }
  else         { in = wproj; out = oproj; cols = 1024; n0 = (bx - 48) * 64; }
  int k0 = blockIdx.y * 64;
  int tid = threadIdx.x;
#pragma unroll
  for (int i = 0; i < 16; ++i) {
    int e = i * 256 + tid;
    int kk = e >> 6, nn = e & 63;
    t[kk][nn] = f2bf(in[(size_t)(k0 + kk) * cols + n0 + nn]);
  }
  __syncthreads();
#pragma unroll
  for (int i = 0; i < 16; ++i) {
    int e = i * 256 + tid;
    int nn = e >> 6, kk = e & 63;
    out[(size_t)(n0 + nn) * 1024 + k0 + kk] = t[kk][nn];
  }
}

// ---------------- GEMM: 256x256 tile, BK=32, 8 waves, counted-lgkmcnt overlap ---------
// (unchanged from round 2 except Q scale constant: 0.125*log2(e) so attn can use exp2)
template <int MODE>
__global__ __launch_bounds__(512, 2) void gemm256(const unsigned short* __restrict__ A,
                                                  const unsigned short* __restrict__ Bt,
                                                  unsigned short* __restrict__ Qt,
                                                  unsigned short* __restrict__ Kw,
                                                  unsigned short* __restrict__ Vt,
                                                  const float* __restrict__ bias,
                                                  float* __restrict__ Out) {
  __shared__ alignas(16) unsigned short S[4][2][8192];   // [buf][A|B][256r * 32k]

  const int tid = threadIdx.x;
  const int w = tid >> 6, lane = tid & 63;
  const int l15 = lane & 15, quad = lane >> 4;
  const int wm = w >> 2, wn = w & 3;            // 2 x 4 wave grid; wave tile 128m x 64n
  const int rt = blockIdx.x, ct = blockIdx.y;

  // fragment ds_read_b128 byte offset: row l15 (64B rows), k-chunk quad, chunk-swizzled
  const int lane_off = l15 * 64 + ((quad * 16) ^ ((l15 & 6) << 3));
  const int abase = wm * 8192;                  // wave's A row-block byte base (128 rows)
  const int bbase = wn * 4096;                  // wave's B col-block byte base (64 rows)

  // staging: wave w fills 1KB slots {2w, 2w+1} of each 16KB panel; per-lane source is
  // inverse-swizzled: lane i -> row lr = i>>2 (of 16-row slot), k-chunk (i&3)^((i>>3)&3)
  const int s0 = w * 2, s1 = s0 + 1;
  const int lr = lane >> 2;
  const int lc = (lane & 3) ^ ((lane >> 3) & 3);
  const unsigned short* gA0 = A + (size_t)(rt * 256 + s0 * 16 + lr) * 1024 + lc * 8;
  const unsigned short* gA1 = A + (size_t)(rt * 256 + s1 * 16 + lr) * 1024 + lc * 8;
  const unsigned short* gB0 = Bt + (size_t)(ct * 256 + s0 * 16 + lr) * 1024 + lc * 8;
  const unsigned short* gB1 = Bt + (size_t)(ct * 256 + s1 * 16 + lr) * 1024 + lc * 8;

  f32x4 acc[8][4] = {};
  short8 avX[4], bvX[4], avY[4], bvY[4], aw[4];

#define STAGE(KT) {                                                            \
    unsigned short* ls = &S[(KT) & 3][0][0];                                   \
    async_cp16(ls + s0 * 512, gA0 + (KT) * 32);                                \
    async_cp16(ls + s1 * 512, gA1 + (KT) * 32);                                \
    async_cp16(ls + 8192 + s0 * 512, gB0 + (KT) * 32);                         \
    async_cp16(ls + 8192 + s1 * 512, gB1 + (KT) * 32); }

#define RD_G0(KT, av, bv) {                                                    \
    const char* pa_ = (const char*)&S[(KT) & 3][0][0] + abase;                 \
    const char* pb_ = (const char*)&S[(KT) & 3][1][0] + bbase;                 \
    _Pragma("unroll") for (int mt = 0; mt < 4; ++mt)                           \
        av[mt] = *(const short8*)(pa_ + mt * 1024 + lane_off);                 \
    _Pragma("unroll") for (int nt = 0; nt < 4; ++nt)                           \
        bv[nt] = *(const short8*)(pb_ + nt * 1024 + lane_off); }

#define RD_G1(KT) {                                                            \
    const char* pa_ = (const char*)&S[(KT) & 3][0][0] + abase + 4096;          \
    _Pragma("unroll") for (int mt = 0; mt < 4; ++mt)                           \
        aw[mt] = *(const short8*)(pa_ + mt * 1024 + lane_off); }

#define MM_G0(av, bv)                                                          \
  __builtin_amdgcn_s_setprio(1);                                               \
  _Pragma("unroll") for (int mt = 0; mt < 4; ++mt)                             \
    _Pragma("unroll") for (int nt = 0; nt < 4; ++nt)                           \
        acc[mt][nt] = __builtin_amdgcn_mfma_f32_16x16x32_bf16(av[mt], bv[nt],  \
                                                              acc[mt][nt], 0, 0, 0); \
  __builtin_amdgcn_s_setprio(0);

#define MM_G1(bv)                                                              \
  __builtin_amdgcn_s_setprio(1);                                               \
  _Pragma("unroll") for (int mt = 0; mt < 4; ++mt)                             \
    _Pragma("unroll") for (int nt = 0; nt < 4; ++nt)                           \
        acc[4 + mt][nt] = __builtin_amdgcn_mfma_f32_16x16x32_bf16(aw[mt], bv[nt], \
                                                                  acc[4 + mt][nt], 0, 0, 0); \
  __builtin_amdgcn_s_setprio(0);

#define LGKM(N) do { asm volatile("s_waitcnt lgkmcnt(" #N ")" ::: "memory");   \
                     __builtin_amdgcn_sched_barrier(0); } while (0)
#define VMC(N)  asm volatile("s_waitcnt vmcnt(" #N ")" ::: "memory")

#define TILE(KT, avC, bvC, avN, bvN) {                                         \
    RD_G1(KT);                     /* 4 ds: g1 A-frags                     */  \
    STAGE((KT) + 2);               /* 4 vm: 2 tiles ahead                  */  \
    LGKM(4);                       /* g0(KT) regs ready (12 -> 4 pending)  */  \
    MM_G0(avC, bvC);                                                           \
    __builtin_amdgcn_sched_barrier(0);                                         \
    VMC(4);                        /* KT+1's 4 loads landed (8 in flight)  */  \
    __builtin_amdgcn_s_barrier();  /* buf[KT+1] visible                    */  \
    RD_G0((KT) + 1, avN, bvN);     /* 8 ds into other reg set              */  \
    LGKM(8);                       /* g1(KT) regs ready                    */  \
    MM_G1(bvC);                                                                \
  }

  // prologue: stage tiles 0,1; make tile 0 visible; preload its g0 frags
  STAGE(0); STAGE(1);
  VMC(4);
  __builtin_amdgcn_s_barrier();
  RD_G0(0, avX, bvX);

#pragma unroll 1
  for (int kt = 0; kt < 30; kt += 2) {
    TILE(kt, avX, bvX, avY, bvY);
    TILE(kt + 1, avY, bvY, avX, bvX);
  }
  // kt = 30: no staging left; must fully drain vmcnt for tile 31
  RD_G1(30);
  LGKM(4);
  MM_G0(avX, bvX);
  __builtin_amdgcn_sched_barrier(0);
  VMC(0);
  __builtin_amdgcn_s_barrier();
  RD_G0(31, avY, bvY);
  LGKM(8);
  MM_G1(bvX);
  // kt = 31
  RD_G1(31);
  LGKM(4);
  MM_G0(avY, bvY);
  LGKM(0);
  __builtin_amdgcn_sched_barrier(0);
  MM_G1(bvY);

#undef TILE
#undef VMC
#undef LGKM
#undef MM_G1
#undef MM_G0
#undef RD_G1
#undef RD_G0
#undef STAGE

  // epilogue: C/D layout col = l15 (B side), row = quad*4 + r (A side)
  if (MODE == 0) {
    const int b = rt >> 2;                       // 256-row tiles align with batches
    const int colg = ct * 4 + wn;                // global 64-col group, 0..47
    const int sel = colg >> 4;                   // 0=Q, 1=K, 2=V
    const int h = colg & 15;
    const int bh = b * 16 + h;
    const int nbase = (rt & 3) * 256 + wm * 128 + quad * 4;   // row within batch
#pragma unroll
    for (int nf = 0; nf < 4; ++nf) {
      const int d = nf * 16 + l15;
#pragma unroll
      for (int rf = 0; rf < 8; ++rf) {
        const int n0 = nbase + rf * 16;
        if (sel == 1) {
          // K: [bh][m][d] layout, lane holds fixed d for 4 consecutive n -> scalar stores
#pragma unroll
          for (int r = 0; r < 4; ++r)
            Kw[((size_t)bh * MP_ + P_ + n0 + r) * D_ + d] = f2bf(acc[rf][nf][r]);
        } else if (sel == 0) {
          // softmax scale * log2(e) folded into Q (attn uses exp2)
          ushort4 p4;
          p4.x = f2bf(acc[rf][nf][0] * 0.18033688f);
          p4.y = f2bf(acc[rf][nf][1] * 0.18033688f);
          p4.z = f2bf(acc[rf][nf][2] * 0.18033688f);
          p4.w = f2bf(acc[rf][nf][3] * 0.18033688f);
          *(ushort4*)&Qt[((size_t)bh * D_ + d) * N_ + n0] = p4;
        } else {
          ushort4 p4;
          p4.x = f2bf(acc[rf][nf][0]);
          p4.y = f2bf(acc[rf][nf][1]);
          p4.z = f2bf(acc[rf][nf][2]);
          p4.w = f2bf(acc[rf][nf][3]);
          *(ushort4*)&Vt[((size_t)bh * D_ + d) * MP_ + P_ + n0] = p4;
        }
      }
    }
  } else {
#pragma unroll
    for (int nf = 0; nf < 4; ++nf) {
      const int col = ct * 256 + wn * 64 + nf * 16 + l15;
      const float bs = bias[col];
#pragma unroll
      for (int rf = 0; rf < 8; ++rf) {
#pragma unroll
        for (int r = 0; r < 4; ++r) {
          const int row = rt * 256 + wm * 128 + rf * 16 + quad * 4 + r;
          Out[(size_t)row * C_ + col] = acc[rf][nf][r] + bs;   // d_out is FP32
        }
      }
    }
  }
}

// ---------------- attention ----------------
// grid (256 bh, 8 qt) -- bh fastest so all 8 qt-blocks of one bh land on ONE XCD
// (linear id = qt*256+bh, id%8 = bh%8) -> K/V L2 reuse across qt.
// block 256 = 4 waves x 32 q-rows. Swapped QK^T: s = mfma(K, Q) -> lane l15 = q-row,
// P lane-local; softmax fully in-register (cvt_pk + quad-exchange via shfl);
// no P LDS buffer, no validity mask (pad K rows = 0 -> P = 1, V pad = 0 -> PV ok;
// den subtracts the exact 48-row pad count after the quad reduce).
__global__ __launch_bounds__(256) void attn_kernel(const unsigned short* __restrict__ Qt,
                                                   const unsigned short* __restrict__ Kw,
                                                   const unsigned short* __restrict__ Vt,
                                                   unsigned short* __restrict__ Ao) {
  __shared__ unsigned short Ks[4096];      // 2 panels [64 m][32 d]
  __shared__ unsigned short Vs[4096];      // 2 panels [64 d][32 m]
  const int tid = threadIdx.x;
  const int w = tid >> 6, lane = tid & 63;
  const int l15 = lane & 15, quad = lane >> 4, q8 = quad * 8;
  const int bh = blockIdx.x, qt = blockIdx.y;

  // Q B-frags from Q^T[bh][d][n]: lane = q-col = l15, k-elem j of half h = d = h*32+q8+j
  short8 aq[2][2];
#pragma unroll
  for (int mq = 0; mq < 2; ++mq) {
    int qrow = qt * 128 + w * 32 + mq * 16 + l15;
    const unsigned short* Qb = Qt + (size_t)bh * D_ * N_ + qrow;
#pragma unroll
    for (int h = 0; h < 2; ++h)
#pragma unroll
      for (int j = 0; j < 8; ++j)
        aq[mq][h][j] = (short)Qb[(size_t)(h * 32 + q8 + j) * N_];
  }

  f32x4 oacc[2][4] = {};
  float den[2] = {};

  const unsigned short* Kbh = Kw + (size_t)bh * MP_ * 64;
  const unsigned short* Vbh = Vt + (size_t)bh * 64 * MP_;

  for (int ch = 0; ch < 17; ++ch) {
    __syncthreads();
#pragma unroll
    for (int r = 0; r < 2; ++r) {
      int c = r * 256 + tid;
      int p = c >> 8, mrow = (c >> 2) & 63, s = c & 3;   // chunk -> (panel, row, 16B seg)
      async_cp16(&Ks[(r * 256 + (w << 6)) * 8], Kbh + (size_t)(ch * 64 + mrow) * 64 + p * 32 + s * 8);
      async_cp16(&Vs[(r * 256 + (w << 6)) * 8], Vbh + (size_t)mrow * MP_ + ch * 64 + p * 32 + s * 8);
    }
    __syncthreads();

    // QK^T (swapped: A=K rows=m, B=Q cols=q) -> lane holds S[q=l15][m=ct2*16+quad*4+r]
    // pk_[mq][ct2*2+p] = bf16x2 of P at m-pair (16*ct2 + 4*quad + 2p, +1)
    unsigned int pk_[2][8];
#pragma unroll
    for (int ct2 = 0; ct2 < 4; ++ct2) {
      short8 k0 = *(const short8*)&Ks[(ct2 * 16 + l15) * 32 + q8];         // d 0..31
      short8 k1 = *(const short8*)&Ks[2048 + (ct2 * 16 + l15) * 32 + q8];  // d 32..63
#pragma unroll
      for (int mq = 0; mq < 2; ++mq) {
        f32x4 s = {};
        s = __builtin_amdgcn_mfma_f32_16x16x32_bf16(k0, aq[mq][0], s, 0, 0, 0);
        s = __builtin_amdgcn_mfma_f32_16x16x32_bf16(k1, aq[mq][1], s, 0, 0, 0);
        float p0 = exp2_hw(s[0]), p1 = exp2_hw(s[1]);
        float p2 = exp2_hw(s[2]), p3 = exp2_hw(s[3]);
        den[mq] += (p0 + p1) + (p2 + p3);
        pk_[mq][ct2 * 2]     = cvt_pk_bf16(p0, p1);
        pk_[mq][ct2 * 2 + 1] = cvt_pk_bf16(p2, p3);
      }
    }

    // quad-exchange: build PV A-frag word wj of half h: m-pair m' = 32h + 8*quad + 2wj.
    // source lane (qv = 2(quad&1)+(wj>>1), same l15), source reg idx = 4h+2*(quad>>1)+(wj&1)
    // -> pull both candidate regs, select by reader's quad bit 1. Verified bijection.
    short8 ap[2][2];
#pragma unroll
    for (int mq = 0; mq < 2; ++mq)
#pragma unroll
      for (int h = 0; h < 2; ++h) {
        union { unsigned int u[4]; short8 s; } fr;
#pragma unroll
        for (int wj = 0; wj < 4; ++wj) {
          int srcl = (((quad & 1) << 1) + (wj >> 1)) * 16 + l15;
          unsigned int a = (unsigned int)__shfl((int)pk_[mq][4 * h + (wj & 1)], srcl);
          unsigned int b2 = (unsigned int)__shfl((int)pk_[mq][4 * h + 2 + (wj & 1)], srcl);
          fr.u[wj] = (quad & 2) ? b2 : a;
        }
        ap[mq][h] = fr.s;
      }

    // PV: A=P (rows=q), B=V^T (cols=d)
#pragma unroll
    for (int dt = 0; dt < 4; ++dt) {
      short8 b0 = *(const short8*)&Vs[(dt * 16 + l15) * 32 + q8];          // m 0..31
      short8 b1 = *(const short8*)&Vs[2048 + (dt * 16 + l15) * 32 + q8];   // m 32..63
#pragma unroll
      for (int mq = 0; mq < 2; ++mq) {
        oacc[mq][dt] = __builtin_amdgcn_mfma_f32_16x16x32_bf16(ap[mq][0], b0, oacc[mq][dt], 0, 0, 0);
        oacc[mq][dt] = __builtin_amdgcn_mfma_f32_16x16x32_bf16(ap[mq][1], b1, oacc[mq][dt], 0, 0, 0);
      }
    }
  }

  // den: each lane holds the partial over its own m-slots for q=l15; quads partition m.
#pragma unroll
  for (int mq = 0; mq < 2; ++mq) {
    float d2 = den[mq];
    d2 += __shfl_xor(d2, 16);
    d2 += __shfl_xor(d2, 32);
    den[mq] = d2 - 48.0f;      // remove exp2(0)=1 from the 48 zero-pad rows (exact)
  }

  // broadcast den to output layout (row = quad*4+r) and normalize
  float rin[2][4];
#pragma unroll
  for (int mq = 0; mq < 2; ++mq)
#pragma unroll
    for (int r = 0; r < 4; ++r)
      rin[mq][r] = 1.f / __shfl(den[mq], quad * 4 + r);

  int b = bh >> 4, h = bh & 15;
#pragma unroll
  for (int mq = 0; mq < 2; ++mq)
#pragma unroll
    for (int dt = 0; dt < 4; ++dt)
#pragma unroll
      for (int r = 0; r < 4; ++r) {
        int qrow = qt * 128 + w * 32 + mq * 16 + quad * 4 + r;
        size_t dst = ((size_t)(b * N_ + qrow)) * C_ + h * 64 + dt * 16 + l15;
        Ao[dst] = f2bf(oacc[mq][dt][r] * rin[mq][r]);
      }
}

// ---------------- launch ----------------

extern "C" void kernel_launch(void* const* d_in, const int* in_sizes, int n_in,
                              void* d_out, int out_size, void* d_ws, size_t ws_size,
                              hipStream_t stream) {
  const float* x      = (const float*)d_in[0];
  const float* pk     = (const float*)d_in[1];
  const float* pv     = (const float*)d_in[2];
  const float* w_qkv  = (const float*)d_in[3];
  const float* w_proj = (const float*)d_in[4];
  const float* b_proj = (const float*)d_in[5];

  char* ws = (char*)d_ws;
  unsigned short* xb     = (unsigned short*)(ws);                 // 33,554,432 B
  unsigned short* wqkvT  = (unsigned short*)(ws + 33554432);      //  6,291,456 B
  unsigned short* wprojT = (unsigned short*)(ws + 39845888);      //  2,097,152 B
  unsigned short* Qt     = (unsigned short*)(ws + 41943040);      // 33,554,432 B
  unsigned short* Kw     = (unsigned short*)(ws + 75497472);      // 35,651,584 B
  unsigned short* Vt     = (unsigned short*)(ws + 111149056);     // 35,651,584 B
  unsigned short* attn   = xb;  // alias: xb is dead after the QKV GEMM

  prep_kernel<<<20480, 256, 0, stream>>>(x, pk, pv, xb, Kw, Vt);
  transpose_cast_kernel<<<dim3(64, 16), 256, 0, stream>>>(w_qkv, w_proj, wqkvT, wprojT);

  gemm256<0><<<dim3(64, 12), 512, 0, stream>>>(xb, wqkvT, Qt, Kw, Vt, nullptr, nullptr);
  attn_kernel<<<dim3(256, 8), 256, 0, stream>>>(Qt, Kw, Vt, attn);
  gemm256<1><<<dim3(64, 4), 512, 0, stream>>>(attn, wprojT, nullptr, nullptr, nullptr,
                                              b_proj, (float*)d_out);
}

// Round 6
// 391.833 us; speedup vs baseline: 1.1246x; 1.0361x over previous
//
#include <hip/hip_runtime.h>
#include <stdint.h>

// Problem constants
#define B_  16
#define N_  1024
#define C_  1024
#define H_  16
#define D_  64
#define P_  16
#define M_  1040           // P + N
#define MP_ 1088           // M padded to 17*64

typedef __attribute__((ext_vector_type(8))) short short8;   // 8 bf16 = 4 VGPRs
typedef __attribute__((ext_vector_type(4))) float f32x4;    // MFMA C/D frag

__device__ __forceinline__ unsigned short f2bf(float f) {
  unsigned int u = __float_as_uint(f);
  u += 0x7fffu + ((u >> 16) & 1u);          // RNE
  return (unsigned short)(u >> 16);
}

__device__ __forceinline__ unsigned int cvt_pk_bf16(float lo, float hi) {
  unsigned int r;
  asm("v_cvt_pk_bf16_f32 %0, %1, %2" : "=v"(r) : "v"(lo), "v"(hi));
  return r;
}

// 2^x via the HW transcendental unit (v_exp_f32 IS exp2 on gfx9xx).
__device__ __forceinline__ float exp2_hw(float x) {
  float r;
  asm("v_exp_f32 %0, %1" : "=v"(r) : "v"(x));
  return r;
}

// async global->LDS, 16B per lane. LDS dest must be wave-uniform base (+lane*16 implicit).
__device__ __forceinline__ void async_cp16(void* lds, const void* g) {
  __builtin_amdgcn_global_load_lds(
      (__attribute__((address_space(1))) void*)(void*)g,
      (__attribute__((address_space(3))) void*)lds,
      16, 0, 0);
}

// ---------------- prep kernels (merged: 2 launches) ----------------

// blocks [0,16384): x fp32->bf16 cast.  blocks [16384,20480): K prefix/pad + V^T prefix/pad.
__global__ void prep_kernel(const float* __restrict__ x, const float* __restrict__ pk,
                            const float* __restrict__ pv, unsigned short* __restrict__ xb,
                            unsigned short* __restrict__ Kw, unsigned short* __restrict__ Vt) {
  int bid = blockIdx.x;
  if (bid < 16384) {
    int i = (bid * 256 + threadIdx.x) * 4;
    float4 v = *(const float4*)(x + i);
    ushort4 o;
    o.x = f2bf(v.x); o.y = f2bf(v.y); o.z = f2bf(v.z); o.w = f2bf(v.w);
    *(ushort4*)(xb + i) = o;
  } else {
    int idx = (bid - 16384) * 256 + threadIdx.x;   // 1,048,576
    {  // K: d fastest (coalesced dst + src)
      int d = idx & 63, rr = (idx >> 6) & 63, bh = idx >> 12;
      int row = (rr < P_) ? rr : (1024 + rr);
      float kv = 0.f;
      if (rr < P_) { int b = bh >> 4, h = bh & 15; kv = pk[(b * P_ + rr) * C_ + h * D_ + d]; }
      Kw[((size_t)bh * MP_ + row) * D_ + d] = f2bf(kv);
    }
    {  // V^T: row-slot fastest (coalesced dst; tiny strided src absorbed by L2)
      int mm = idx & 63, d = (idx >> 6) & 63, bh = idx >> 12;
      int row = (mm < P_) ? mm : (1024 + mm);
      float vv = 0.f;
      if (mm < P_) { int b = bh >> 4, h = bh & 15; vv = pv[(b * P_ + mm) * C_ + h * D_ + d]; }
      Vt[((size_t)bh * D_ + d) * MP_ + row] = f2bf(vv);
    }
  }
}

// both weight transposes in one launch: [1024 k][cols n] fp32 -> [n][1024 k] bf16.
// blockIdx.x < 48 -> w_qkv (cols=3072); else w_proj (cols=1024).
__global__ void transpose_cast_kernel(const float* __restrict__ wqkv,
                                      const float* __restrict__ wproj,
                                      unsigned short* __restrict__ oqkv,
                                      unsigned short* __restrict__ oproj) {
  __shared__ unsigned short t[64][68];   // pad 68: breaks bank aliasing on strided read
  int bx = blockIdx.x;
  const float* in;  unsigned short* out;  int cols, n0;
  if (bx < 48) { in = wqkv;  out = oqkv;  cols = 3072; n0 = bx * 64; }
  else         { in = wproj; out = oproj; cols = 1024; n0 = (bx - 48) * 64; }
  int k0 = blockIdx.y * 64;
  int tid = threadIdx.x;
#pragma unroll
  for (int i = 0; i < 16; ++i) {
    int e = i * 256 + tid;
    int kk = e >> 6, nn = e & 63;
    t[kk][nn] = f2bf(in[(size_t)(k0 + kk) * cols + n0 + nn]);
  }
  __syncthreads();
#pragma unroll
  for (int i = 0; i < 16; ++i) {
    int e = i * 256 + tid;
    int nn = e >> 6, kk = e & 63;
    out[(size_t)(n0 + nn) * 1024 + k0 + kk] = t[kk][nn];
  }
}

// ---------------- GEMM: 256x256 tile, BK=32, 8 waves, counted-lgkmcnt overlap ---------
// (unchanged; Q scale constant = 0.125*log2(e) so attn can use exp2)
template <int MODE>
__global__ __launch_bounds__(512, 2) void gemm256(const unsigned short* __restrict__ A,
                                                  const unsigned short* __restrict__ Bt,
                                                  unsigned short* __restrict__ Qt,
                                                  unsigned short* __restrict__ Kw,
                                                  unsigned short* __restrict__ Vt,
                                                  const float* __restrict__ bias,
                                                  float* __restrict__ Out) {
  __shared__ alignas(16) unsigned short S[4][2][8192];   // [buf][A|B][256r * 32k]

  const int tid = threadIdx.x;
  const int w = tid >> 6, lane = tid & 63;
  const int l15 = lane & 15, quad = lane >> 4;
  const int wm = w >> 2, wn = w & 3;            // 2 x 4 wave grid; wave tile 128m x 64n
  const int rt = blockIdx.x, ct = blockIdx.y;

  // fragment ds_read_b128 byte offset: row l15 (64B rows), k-chunk quad, chunk-swizzled
  const int lane_off = l15 * 64 + ((quad * 16) ^ ((l15 & 6) << 3));
  const int abase = wm * 8192;                  // wave's A row-block byte base (128 rows)
  const int bbase = wn * 4096;                  // wave's B col-block byte base (64 rows)

  // staging: wave w fills 1KB slots {2w, 2w+1} of each 16KB panel; per-lane source is
  // inverse-swizzled: lane i -> row lr = i>>2 (of 16-row slot), k-chunk (i&3)^((i>>3)&3)
  const int s0 = w * 2, s1 = s0 + 1;
  const int lr = lane >> 2;
  const int lc = (lane & 3) ^ ((lane >> 3) & 3);
  const unsigned short* gA0 = A + (size_t)(rt * 256 + s0 * 16 + lr) * 1024 + lc * 8;
  const unsigned short* gA1 = A + (size_t)(rt * 256 + s1 * 16 + lr) * 1024 + lc * 8;
  const unsigned short* gB0 = Bt + (size_t)(ct * 256 + s0 * 16 + lr) * 1024 + lc * 8;
  const unsigned short* gB1 = Bt + (size_t)(ct * 256 + s1 * 16 + lr) * 1024 + lc * 8;

  f32x4 acc[8][4] = {};
  short8 avX[4], bvX[4], avY[4], bvY[4], aw[4];

#define STAGE(KT) {                                                            \
    unsigned short* ls = &S[(KT) & 3][0][0];                                   \
    async_cp16(ls + s0 * 512, gA0 + (KT) * 32);                                \
    async_cp16(ls + s1 * 512, gA1 + (KT) * 32);                                \
    async_cp16(ls + 8192 + s0 * 512, gB0 + (KT) * 32);                         \
    async_cp16(ls + 8192 + s1 * 512, gB1 + (KT) * 32); }

#define RD_G0(KT, av, bv) {                                                    \
    const char* pa_ = (const char*)&S[(KT) & 3][0][0] + abase;                 \
    const char* pb_ = (const char*)&S[(KT) & 3][1][0] + bbase;                 \
    _Pragma("unroll") for (int mt = 0; mt < 4; ++mt)                           \
        av[mt] = *(const short8*)(pa_ + mt * 1024 + lane_off);                 \
    _Pragma("unroll") for (int nt = 0; nt < 4; ++nt)                           \
        bv[nt] = *(const short8*)(pb_ + nt * 1024 + lane_off); }

#define RD_G1(KT) {                                                            \
    const char* pa_ = (const char*)&S[(KT) & 3][0][0] + abase + 4096;          \
    _Pragma("unroll") for (int mt = 0; mt < 4; ++mt)                           \
        aw[mt] = *(const short8*)(pa_ + mt * 1024 + lane_off); }

#define MM_G0(av, bv)                                                          \
  __builtin_amdgcn_s_setprio(1);                                               \
  _Pragma("unroll") for (int mt = 0; mt < 4; ++mt)                             \
    _Pragma("unroll") for (int nt = 0; nt < 4; ++nt)                           \
        acc[mt][nt] = __builtin_amdgcn_mfma_f32_16x16x32_bf16(av[mt], bv[nt],  \
                                                              acc[mt][nt], 0, 0, 0); \
  __builtin_amdgcn_s_setprio(0);

#define MM_G1(bv)                                                              \
  __builtin_amdgcn_s_setprio(1);                                               \
  _Pragma("unroll") for (int mt = 0; mt < 4; ++mt)                             \
    _Pragma("unroll") for (int nt = 0; nt < 4; ++nt)                           \
        acc[4 + mt][nt] = __builtin_amdgcn_mfma_f32_16x16x32_bf16(aw[mt], bv[nt], \
                                                                  acc[4 + mt][nt], 0, 0, 0); \
  __builtin_amdgcn_s_setprio(0);

#define LGKM(N) do { asm volatile("s_waitcnt lgkmcnt(" #N ")" ::: "memory");   \
                     __builtin_amdgcn_sched_barrier(0); } while (0)
#define VMC(N)  asm volatile("s_waitcnt vmcnt(" #N ")" ::: "memory")

#define TILE(KT, avC, bvC, avN, bvN) {                                         \
    RD_G1(KT);                     /* 4 ds: g1 A-frags                     */  \
    STAGE((KT) + 2);               /* 4 vm: 2 tiles ahead                  */  \
    LGKM(4);                       /* g0(KT) regs ready (12 -> 4 pending)  */  \
    MM_G0(avC, bvC);                                                           \
    __builtin_amdgcn_sched_barrier(0);                                         \
    VMC(4);                        /* KT+1's 4 loads landed (8 in flight)  */  \
    __builtin_amdgcn_s_barrier();  /* buf[KT+1] visible                    */  \
    RD_G0((KT) + 1, avN, bvN);     /* 8 ds into other reg set              */  \
    LGKM(8);                       /* g1(KT) regs ready                    */  \
    MM_G1(bvC);                                                                \
  }

  // prologue: stage tiles 0,1; make tile 0 visible; preload its g0 frags
  STAGE(0); STAGE(1);
  VMC(4);
  __builtin_amdgcn_s_barrier();
  RD_G0(0, avX, bvX);

#pragma unroll 1
  for (int kt = 0; kt < 30; kt += 2) {
    TILE(kt, avX, bvX, avY, bvY);
    TILE(kt + 1, avY, bvY, avX, bvX);
  }
  // kt = 30: no staging left; must fully drain vmcnt for tile 31
  RD_G1(30);
  LGKM(4);
  MM_G0(avX, bvX);
  __builtin_amdgcn_sched_barrier(0);
  VMC(0);
  __builtin_amdgcn_s_barrier();
  RD_G0(31, avY, bvY);
  LGKM(8);
  MM_G1(bvX);
  // kt = 31
  RD_G1(31);
  LGKM(4);
  MM_G0(avY, bvY);
  LGKM(0);
  __builtin_amdgcn_sched_barrier(0);
  MM_G1(bvY);

#undef TILE
#undef VMC
#undef LGKM
#undef MM_G1
#undef MM_G0
#undef RD_G1
#undef RD_G0
#undef STAGE

  // epilogue: C/D layout col = l15 (B side), row = quad*4 + r (A side)
  if (MODE == 0) {
    const int b = rt >> 2;                       // 256-row tiles align with batches
    const int colg = ct * 4 + wn;                // global 64-col group, 0..47
    const int sel = colg >> 4;                   // 0=Q, 1=K, 2=V
    const int h = colg & 15;
    const int bh = b * 16 + h;
    const int nbase = (rt & 3) * 256 + wm * 128 + quad * 4;   // row within batch
#pragma unroll
    for (int nf = 0; nf < 4; ++nf) {
      const int d = nf * 16 + l15;
#pragma unroll
      for (int rf = 0; rf < 8; ++rf) {
        const int n0 = nbase + rf * 16;
        if (sel == 1) {
          // K: [bh][m][d] layout, lane holds fixed d for 4 consecutive n -> scalar stores
#pragma unroll
          for (int r = 0; r < 4; ++r)
            Kw[((size_t)bh * MP_ + P_ + n0 + r) * D_ + d] = f2bf(acc[rf][nf][r]);
        } else if (sel == 0) {
          // softmax scale * log2(e) folded into Q (attn uses exp2)
          ushort4 p4;
          p4.x = f2bf(acc[rf][nf][0] * 0.18033688f);
          p4.y = f2bf(acc[rf][nf][1] * 0.18033688f);
          p4.z = f2bf(acc[rf][nf][2] * 0.18033688f);
          p4.w = f2bf(acc[rf][nf][3] * 0.18033688f);
          *(ushort4*)&Qt[((size_t)bh * D_ + d) * N_ + n0] = p4;
        } else {
          ushort4 p4;
          p4.x = f2bf(acc[rf][nf][0]);
          p4.y = f2bf(acc[rf][nf][1]);
          p4.z = f2bf(acc[rf][nf][2]);
          p4.w = f2bf(acc[rf][nf][3]);
          *(ushort4*)&Vt[((size_t)bh * D_ + d) * MP_ + P_ + n0] = p4;
        }
      }
    }
  } else {
#pragma unroll
    for (int nf = 0; nf < 4; ++nf) {
      const int col = ct * 256 + wn * 64 + nf * 16 + l15;
      const float bs = bias[col];
#pragma unroll
      for (int rf = 0; rf < 8; ++rf) {
#pragma unroll
        for (int r = 0; r < 4; ++r) {
          const int row = rt * 256 + wm * 128 + rf * 16 + quad * 4 + r;
          Out[(size_t)row * C_ + col] = acc[rf][nf][r] + bs;   // d_out is FP32
        }
      }
    }
  }
}

// ---------------- attention ----------------
// grid (256 bh, 8 qt): bh fastest -> all 8 qt-blocks of one bh on ONE XCD (K/V L2 reuse).
// block 256 = 4 waves x 32 q-rows. Swapped QK^T -> in-register softmax (round-3 design).
// THIS ROUND: (a) K/V LDS 16B-chunk XOR swizzle, same involution as gemm256 (reads were
// 8-way bank-conflicted: even l15 -> banks 0-3, odd -> 16-19; swizzle spreads to 2/bank);
// (b) double-buffered K/V with ONE __syncthreads per chunk: stage(ch+1) issues right
// after the barrier, so its HBM/L2 latency hides under compute(ch). Barrier at iter ch
// orders all waves' compute(ch-1) reads of buf[(ch+1)&1] before the overwrite: race-free.
__global__ __launch_bounds__(256) void attn_kernel(const unsigned short* __restrict__ Qt,
                                                   const unsigned short* __restrict__ Kw,
                                                   const unsigned short* __restrict__ Vt,
                                                   unsigned short* __restrict__ Ao) {
  __shared__ unsigned short Ks[2][4096];   // [buf][2 panels [64 m][32 d]], seg-swizzled
  __shared__ unsigned short Vs[2][4096];   // [buf][2 panels [64 d][32 m]], seg-swizzled
  const int tid = threadIdx.x;
  const int w = tid >> 6, lane = tid & 63;
  const int l15 = lane & 15, quad = lane >> 4, q8 = quad * 8;
  const int bh = blockIdx.x, qt = blockIdx.y;

  // Q B-frags from Q^T[bh][d][n]: lane = q-col = l15, k-elem j of half h = d = h*32+q8+j
  short8 aq[2][2];
#pragma unroll
  for (int mq = 0; mq < 2; ++mq) {
    int qrow = qt * 128 + w * 32 + mq * 16 + l15;
    const unsigned short* Qb = Qt + (size_t)bh * D_ * N_ + qrow;
#pragma unroll
    for (int h = 0; h < 2; ++h)
#pragma unroll
      for (int j = 0; j < 8; ++j)
        aq[mq][h][j] = (short)Qb[(size_t)(h * 32 + q8 + j) * N_];
  }

  f32x4 oacc[2][4] = {};
  float den[2] = {};

  const unsigned short* Kbh = Kw + (size_t)bh * MP_ * 64;
  const unsigned short* Vbh = Vt + (size_t)bh * 64 * MP_;

  // staging: lane -> (row-in-slot = lane>>2, inverse-swizzled 16B seg); LDS dest linear
  const int mrow = w * 16 + (lane >> 2);
  const int sw2 = (lane & 3) ^ ((lane >> 3) & 3);
  // fragment read byte offset within a row: swizzled (2 lanes/bank -> conflict-free)
  const int qo = (quad * 16) ^ ((l15 & 6) << 3);

#define STAGE_KV(CH, BUF) {                                                    \
    _Pragma("unroll") for (int r = 0; r < 2; ++r) {                            \
      async_cp16(&Ks[BUF][r * 2048 + w * 512],                                 \
                 Kbh + (size_t)((CH) * 64 + mrow) * 64 + r * 32 + sw2 * 8);    \
      async_cp16(&Vs[BUF][r * 2048 + w * 512],                                 \
                 Vbh + (size_t)mrow * MP_ + (CH) * 64 + r * 32 + sw2 * 8);     \
    } }

  STAGE_KV(0, 0);

#pragma unroll 1
  for (int ch = 0; ch < 17; ++ch) {
    __syncthreads();   // vmcnt(0)+lgkmcnt(0)+barrier: buf[ch&1] landed for ALL waves;
                       // all waves finished reading buf[(ch+1)&1] in their iter ch-1
    if (ch + 1 < 17) STAGE_KV(ch + 1, (ch + 1) & 1);   // latency hides under compute(ch)

    const char* Kb = (const char*)&Ks[ch & 1][0];
    const char* Vb = (const char*)&Vs[ch & 1][0];

    // QK^T (swapped: A=K rows=m, B=Q cols=q) -> lane holds S[q=l15][m=ct2*16+quad*4+r]
    unsigned int pk_[2][8];
#pragma unroll
    for (int ct2 = 0; ct2 < 4; ++ct2) {
      short8 k0 = *(const short8*)(Kb + (ct2 * 16 + l15) * 64 + qo);          // d 0..31
      short8 k1 = *(const short8*)(Kb + 4096 + (ct2 * 16 + l15) * 64 + qo);   // d 32..63
#pragma unroll
      for (int mq = 0; mq < 2; ++mq) {
        f32x4 s = {};
        s = __builtin_amdgcn_mfma_f32_16x16x32_bf16(k0, aq[mq][0], s, 0, 0, 0);
        s = __builtin_amdgcn_mfma_f32_16x16x32_bf16(k1, aq[mq][1], s, 0, 0, 0);
        float p0 = exp2_hw(s[0]), p1 = exp2_hw(s[1]);
        float p2 = exp2_hw(s[2]), p3 = exp2_hw(s[3]);
        den[mq] += (p0 + p1) + (p2 + p3);
        pk_[mq][ct2 * 2]     = cvt_pk_bf16(p0, p1);
        pk_[mq][ct2 * 2 + 1] = cvt_pk_bf16(p2, p3);
      }
    }

    // quad-exchange: build PV A-frag word wj of half h: m-pair m' = 32h + 8*quad + 2wj.
    // source lane (qv = 2(quad&1)+(wj>>1), same l15), source reg = 4h+2*(quad>>1)+(wj&1)
    short8 ap[2][2];
#pragma unroll
    for (int mq = 0; mq < 2; ++mq)
#pragma unroll
      for (int h = 0; h < 2; ++h) {
        union { unsigned int u[4]; short8 s; } fr;
#pragma unroll
        for (int wj = 0; wj < 4; ++wj) {
          int srcl = (((quad & 1) << 1) + (wj >> 1)) * 16 + l15;
          unsigned int a = (unsigned int)__shfl((int)pk_[mq][4 * h + (wj & 1)], srcl);
          unsigned int b2 = (unsigned int)__shfl((int)pk_[mq][4 * h + 2 + (wj & 1)], srcl);
          fr.u[wj] = (quad & 2) ? b2 : a;
        }
        ap[mq][h] = fr.s;
      }

    // PV: A=P (rows=q), B=V^T (cols=d)
#pragma unroll
    for (int dt = 0; dt < 4; ++dt) {
      short8 b0 = *(const short8*)(Vb + (dt * 16 + l15) * 64 + qo);           // m 0..31
      short8 b1 = *(const short8*)(Vb + 4096 + (dt * 16 + l15) * 64 + qo);    // m 32..63
#pragma unroll
      for (int mq = 0; mq < 2; ++mq) {
        oacc[mq][dt] = __builtin_amdgcn_mfma_f32_16x16x32_bf16(ap[mq][0], b0, oacc[mq][dt], 0, 0, 0);
        oacc[mq][dt] = __builtin_amdgcn_mfma_f32_16x16x32_bf16(ap[mq][1], b1, oacc[mq][dt], 0, 0, 0);
      }
    }
  }
#undef STAGE_KV

  // den: each lane holds the partial over its own m-slots for q=l15; quads partition m.
#pragma unroll
  for (int mq = 0; mq < 2; ++mq) {
    float d2 = den[mq];
    d2 += __shfl_xor(d2, 16);
    d2 += __shfl_xor(d2, 32);
    den[mq] = d2 - 48.0f;      // remove exp2(0)=1 from the 48 zero-pad rows (exact)
  }

  // broadcast den to output layout (row = quad*4+r) and normalize
  float rin[2][4];
#pragma unroll
  for (int mq = 0; mq < 2; ++mq)
#pragma unroll
    for (int r = 0; r < 4; ++r)
      rin[mq][r] = 1.f / __shfl(den[mq], quad * 4 + r);

  int b = bh >> 4, h = bh & 15;
#pragma unroll
  for (int mq = 0; mq < 2; ++mq)
#pragma unroll
    for (int dt = 0; dt < 4; ++dt)
#pragma unroll
      for (int r = 0; r < 4; ++r) {
        int qrow = qt * 128 + w * 32 + mq * 16 + quad * 4 + r;
        size_t dst = ((size_t)(b * N_ + qrow)) * C_ + h * 64 + dt * 16 + l15;
        Ao[dst] = f2bf(oacc[mq][dt][r] * rin[mq][r]);
      }
}

// ---------------- launch ----------------

extern "C" void kernel_launch(void* const* d_in, const int* in_sizes, int n_in,
                              void* d_out, int out_size, void* d_ws, size_t ws_size,
                              hipStream_t stream) {
  const float* x      = (const float*)d_in[0];
  const float* pk     = (const float*)d_in[1];
  const float* pv     = (const float*)d_in[2];
  const float* w_qkv  = (const float*)d_in[3];
  const float* w_proj = (const float*)d_in[4];
  const float* b_proj = (const float*)d_in[5];

  char* ws = (char*)d_ws;
  unsigned short* xb     = (unsigned short*)(ws);                 // 33,554,432 B
  unsigned short* wqkvT  = (unsigned short*)(ws + 33554432);      //  6,291,456 B
  unsigned short* wprojT = (unsigned short*)(ws + 39845888);      //  2,097,152 B
  unsigned short* Qt     = (unsigned short*)(ws + 41943040);      // 33,554,432 B
  unsigned short* Kw     = (unsigned short*)(ws + 75497472);      // 35,651,584 B
  unsigned short* Vt     = (unsigned short*)(ws + 111149056);     // 35,651,584 B
  unsigned short* attn   = xb;  // alias: xb is dead after the QKV GEMM

  prep_kernel<<<20480, 256, 0, stream>>>(x, pk, pv, xb, Kw, Vt);
  transpose_cast_kernel<<<dim3(64, 16), 256, 0, stream>>>(w_qkv, w_proj, wqkvT, wprojT);

  gemm256<0><<<dim3(64, 12), 512, 0, stream>>>(xb, wqkvT, Qt, Kw, Vt, nullptr, nullptr);
  attn_kernel<<<dim3(256, 8), 256, 0, stream>>>(Qt, Kw, Vt, attn);
  gemm256<1><<<dim3(64, 4), 512, 0, stream>>>(attn, wprojT, nullptr, nullptr, nullptr,
                                              b_proj, (float*)d_out);
}

// Round 7
// 378.858 us; speedup vs baseline: 1.1632x; 1.0342x over previous
//
#include <hip/hip_runtime.h>
#include <stdint.h>

// Problem constants
#define B_  16
#define N_  1024
#define C_  1024
#define H_  16
#define D_  64
#define P_  16
#define M_  1040           // P + N
#define MP_ 1088           // M padded to 17*64

typedef __attribute__((ext_vector_type(8))) short short8;   // 8 bf16 = 4 VGPRs
typedef __attribute__((ext_vector_type(4))) float f32x4;    // MFMA C/D frag

__device__ __forceinline__ unsigned short f2bf(float f) {
  unsigned int u = __float_as_uint(f);
  u += 0x7fffu + ((u >> 16) & 1u);          // RNE
  return (unsigned short)(u >> 16);
}

__device__ __forceinline__ unsigned int cvt_pk_bf16(float lo, float hi) {
  unsigned int r;
  asm("v_cvt_pk_bf16_f32 %0, %1, %2" : "=v"(r) : "v"(lo), "v"(hi));
  return r;
}

// 2^x via the HW transcendental unit (v_exp_f32 IS exp2 on gfx9xx).
__device__ __forceinline__ float exp2_hw(float x) {
  float r;
  asm("v_exp_f32 %0, %1" : "=v"(r) : "v"(x));
  return r;
}

// async global->LDS, 16B per lane. LDS dest must be wave-uniform base (+lane*16 implicit).
__device__ __forceinline__ void async_cp16(void* lds, const void* g) {
  __builtin_amdgcn_global_load_lds(
      (__attribute__((address_space(1))) void*)(void*)g,
      (__attribute__((address_space(3))) void*)lds,
      16, 0, 0);
}

// ---------------- prep kernels (merged: 2 launches) ----------------

// blocks [0,16384): x fp32->bf16 cast.  blocks [16384,20480): K prefix/pad + V^T prefix/pad.
__global__ void prep_kernel(const float* __restrict__ x, const float* __restrict__ pk,
                            const float* __restrict__ pv, unsigned short* __restrict__ xb,
                            unsigned short* __restrict__ Kw, unsigned short* __restrict__ Vt) {
  int bid = blockIdx.x;
  if (bid < 16384) {
    int i = (bid * 256 + threadIdx.x) * 4;
    float4 v = *(const float4*)(x + i);
    ushort4 o;
    o.x = f2bf(v.x); o.y = f2bf(v.y); o.z = f2bf(v.z); o.w = f2bf(v.w);
    *(ushort4*)(xb + i) = o;
  } else {
    int idx = (bid - 16384) * 256 + threadIdx.x;   // 1,048,576
    {  // K: d fastest (coalesced dst + src)
      int d = idx & 63, rr = (idx >> 6) & 63, bh = idx >> 12;
      int row = (rr < P_) ? rr : (1024 + rr);
      float kv = 0.f;
      if (rr < P_) { int b = bh >> 4, h = bh & 15; kv = pk[(b * P_ + rr) * C_ + h * D_ + d]; }
      Kw[((size_t)bh * MP_ + row) * D_ + d] = f2bf(kv);
    }
    {  // V^T: row-slot fastest (coalesced dst; tiny strided src absorbed by L2)
      int mm = idx & 63, d = (idx >> 6) & 63, bh = idx >> 12;
      int row = (mm < P_) ? mm : (1024 + mm);
      float vv = 0.f;
      if (mm < P_) { int b = bh >> 4, h = bh & 15; vv = pv[(b * P_ + mm) * C_ + h * D_ + d]; }
      Vt[((size_t)bh * D_ + d) * MP_ + row] = f2bf(vv);
    }
  }
}

// both weight transposes in one launch: [1024 k][cols n] fp32 -> [n][1024 k] bf16.
// blockIdx.x < 48 -> w_qkv (cols=3072); else w_proj (cols=1024).
__global__ void transpose_cast_kernel(const float* __restrict__ wqkv,
                                      const float* __restrict__ wproj,
                                      unsigned short* __restrict__ oqkv,
                                      unsigned short* __restrict__ oproj) {
  __shared__ unsigned short t[64][68];   // pad 68: breaks bank aliasing on strided read
  int bx = blockIdx.x;
  const float* in;  unsigned short* out;  int cols, n0;
  if (bx < 48) { in = wqkv;  out = oqkv;  cols = 3072; n0 = bx * 64; }
  else         { in = wproj; out = oproj; cols = 1024; n0 = (bx - 48) * 64; }
  int k0 = blockIdx.y * 64;
  int tid = threadIdx.x;
#pragma unroll
  for (int i = 0; i < 16; ++i) {
    int e = i * 256 + tid;
    int kk = e >> 6, nn = e & 63;
    t[kk][nn] = f2bf(in[(size_t)(k0 + kk) * cols + n0 + nn]);
  }
  __syncthreads();
#pragma unroll
  for (int i = 0; i < 16; ++i) {
    int e = i * 256 + tid;
    int nn = e >> 6, kk = e & 63;
    out[(size_t)(n0 + nn) * 1024 + k0 + kk] = t[kk][nn];
  }
}

// ---------------- GEMM: 256x256 tile, BK=32, 8 waves, counted-lgkmcnt overlap ---------
// (unchanged; Q scale constant = 0.125*log2(e) so attn can use exp2)
template <int MODE>
__global__ __launch_bounds__(512, 2) void gemm256(const unsigned short* __restrict__ A,
                                                  const unsigned short* __restrict__ Bt,
                                                  unsigned short* __restrict__ Qt,
                                                  unsigned short* __restrict__ Kw,
                                                  unsigned short* __restrict__ Vt,
                                                  const float* __restrict__ bias,
                                                  float* __restrict__ Out) {
  __shared__ alignas(16) unsigned short S[4][2][8192];   // [buf][A|B][256r * 32k]

  const int tid = threadIdx.x;
  const int w = tid >> 6, lane = tid & 63;
  const int l15 = lane & 15, quad = lane >> 4;
  const int wm = w >> 2, wn = w & 3;            // 2 x 4 wave grid; wave tile 128m x 64n
  const int rt = blockIdx.x, ct = blockIdx.y;

  // fragment ds_read_b128 byte offset: row l15 (64B rows), k-chunk quad, chunk-swizzled
  const int lane_off = l15 * 64 + ((quad * 16) ^ ((l15 & 6) << 3));
  const int abase = wm * 8192;                  // wave's A row-block byte base (128 rows)
  const int bbase = wn * 4096;                  // wave's B col-block byte base (64 rows)

  // staging: wave w fills 1KB slots {2w, 2w+1} of each 16KB panel; per-lane source is
  // inverse-swizzled: lane i -> row lr = i>>2 (of 16-row slot), k-chunk (i&3)^((i>>3)&3)
  const int s0 = w * 2, s1 = s0 + 1;
  const int lr = lane >> 2;
  const int lc = (lane & 3) ^ ((lane >> 3) & 3);
  const unsigned short* gA0 = A + (size_t)(rt * 256 + s0 * 16 + lr) * 1024 + lc * 8;
  const unsigned short* gA1 = A + (size_t)(rt * 256 + s1 * 16 + lr) * 1024 + lc * 8;
  const unsigned short* gB0 = Bt + (size_t)(ct * 256 + s0 * 16 + lr) * 1024 + lc * 8;
  const unsigned short* gB1 = Bt + (size_t)(ct * 256 + s1 * 16 + lr) * 1024 + lc * 8;

  f32x4 acc[8][4] = {};
  short8 avX[4], bvX[4], avY[4], bvY[4], aw[4];

#define STAGE(KT) {                                                            \
    unsigned short* ls = &S[(KT) & 3][0][0];                                   \
    async_cp16(ls + s0 * 512, gA0 + (KT) * 32);                                \
    async_cp16(ls + s1 * 512, gA1 + (KT) * 32);                                \
    async_cp16(ls + 8192 + s0 * 512, gB0 + (KT) * 32);                         \
    async_cp16(ls + 8192 + s1 * 512, gB1 + (KT) * 32); }

#define RD_G0(KT, av, bv) {                                                    \
    const char* pa_ = (const char*)&S[(KT) & 3][0][0] + abase;                 \
    const char* pb_ = (const char*)&S[(KT) & 3][1][0] + bbase;                 \
    _Pragma("unroll") for (int mt = 0; mt < 4; ++mt)                           \
        av[mt] = *(const short8*)(pa_ + mt * 1024 + lane_off);                 \
    _Pragma("unroll") for (int nt = 0; nt < 4; ++nt)                           \
        bv[nt] = *(const short8*)(pb_ + nt * 1024 + lane_off); }

#define RD_G1(KT) {                                                            \
    const char* pa_ = (const char*)&S[(KT) & 3][0][0] + abase + 4096;          \
    _Pragma("unroll") for (int mt = 0; mt < 4; ++mt)                           \
        aw[mt] = *(const short8*)(pa_ + mt * 1024 + lane_off); }

#define MM_G0(av, bv)                                                          \
  __builtin_amdgcn_s_setprio(1);                                               \
  _Pragma("unroll") for (int mt = 0; mt < 4; ++mt)                             \
    _Pragma("unroll") for (int nt = 0; nt < 4; ++nt)                           \
        acc[mt][nt] = __builtin_amdgcn_mfma_f32_16x16x32_bf16(av[mt], bv[nt],  \
                                                              acc[mt][nt], 0, 0, 0); \
  __builtin_amdgcn_s_setprio(0);

#define MM_G1(bv)                                                              \
  __builtin_amdgcn_s_setprio(1);                                               \
  _Pragma("unroll") for (int mt = 0; mt < 4; ++mt)                             \
    _Pragma("unroll") for (int nt = 0; nt < 4; ++nt)                           \
        acc[4 + mt][nt] = __builtin_amdgcn_mfma_f32_16x16x32_bf16(aw[mt], bv[nt], \
                                                                  acc[4 + mt][nt], 0, 0, 0); \
  __builtin_amdgcn_s_setprio(0);

#define LGKM(N) do { asm volatile("s_waitcnt lgkmcnt(" #N ")" ::: "memory");   \
                     __builtin_amdgcn_sched_barrier(0); } while (0)
#define VMC(N)  asm volatile("s_waitcnt vmcnt(" #N ")" ::: "memory")

#define TILE(KT, avC, bvC, avN, bvN) {                                         \
    RD_G1(KT);                     /* 4 ds: g1 A-frags                     */  \
    STAGE((KT) + 2);               /* 4 vm: 2 tiles ahead                  */  \
    LGKM(4);                       /* g0(KT) regs ready (12 -> 4 pending)  */  \
    MM_G0(avC, bvC);                                                           \
    __builtin_amdgcn_sched_barrier(0);                                         \
    VMC(4);                        /* KT+1's 4 loads landed (8 in flight)  */  \
    __builtin_amdgcn_s_barrier();  /* buf[KT+1] visible                    */  \
    RD_G0((KT) + 1, avN, bvN);     /* 8 ds into other reg set              */  \
    LGKM(8);                       /* g1(KT) regs ready                    */  \
    MM_G1(bvC);                                                                \
  }

  // prologue: stage tiles 0,1; make tile 0 visible; preload its g0 frags
  STAGE(0); STAGE(1);
  VMC(4);
  __builtin_amdgcn_s_barrier();
  RD_G0(0, avX, bvX);

#pragma unroll 1
  for (int kt = 0; kt < 30; kt += 2) {
    TILE(kt, avX, bvX, avY, bvY);
    TILE(kt + 1, avY, bvY, avX, bvX);
  }
  // kt = 30: no staging left; must fully drain vmcnt for tile 31
  RD_G1(30);
  LGKM(4);
  MM_G0(avX, bvX);
  __builtin_amdgcn_sched_barrier(0);
  VMC(0);
  __builtin_amdgcn_s_barrier();
  RD_G0(31, avY, bvY);
  LGKM(8);
  MM_G1(bvX);
  // kt = 31
  RD_G1(31);
  LGKM(4);
  MM_G0(avY, bvY);
  LGKM(0);
  __builtin_amdgcn_sched_barrier(0);
  MM_G1(bvY);

#undef TILE
#undef VMC
#undef LGKM
#undef MM_G1
#undef MM_G0
#undef RD_G1
#undef RD_G0
#undef STAGE

  // epilogue: C/D layout col = l15 (B side), row = quad*4 + r (A side)
  if (MODE == 0) {
    const int b = rt >> 2;                       // 256-row tiles align with batches
    const int colg = ct * 4 + wn;                // global 64-col group, 0..47
    const int sel = colg >> 4;                   // 0=Q, 1=K, 2=V
    const int h = colg & 15;
    const int bh = b * 16 + h;
    const int nbase = (rt & 3) * 256 + wm * 128 + quad * 4;   // row within batch
#pragma unroll
    for (int nf = 0; nf < 4; ++nf) {
      const int d = nf * 16 + l15;
#pragma unroll
      for (int rf = 0; rf < 8; ++rf) {
        const int n0 = nbase + rf * 16;
        if (sel == 1) {
          // K: [bh][m][d] layout, lane holds fixed d for 4 consecutive n -> scalar stores
#pragma unroll
          for (int r = 0; r < 4; ++r)
            Kw[((size_t)bh * MP_ + P_ + n0 + r) * D_ + d] = f2bf(acc[rf][nf][r]);
        } else if (sel == 0) {
          // softmax scale * log2(e) folded into Q (attn uses exp2)
          ushort4 p4;
          p4.x = f2bf(acc[rf][nf][0] * 0.18033688f);
          p4.y = f2bf(acc[rf][nf][1] * 0.18033688f);
          p4.z = f2bf(acc[rf][nf][2] * 0.18033688f);
          p4.w = f2bf(acc[rf][nf][3] * 0.18033688f);
          *(ushort4*)&Qt[((size_t)bh * D_ + d) * N_ + n0] = p4;
        } else {
          ushort4 p4;
          p4.x = f2bf(acc[rf][nf][0]);
          p4.y = f2bf(acc[rf][nf][1]);
          p4.z = f2bf(acc[rf][nf][2]);
          p4.w = f2bf(acc[rf][nf][3]);
          *(ushort4*)&Vt[((size_t)bh * D_ + d) * MP_ + P_ + n0] = p4;
        }
      }
    }
  } else {
#pragma unroll
    for (int nf = 0; nf < 4; ++nf) {
      const int col = ct * 256 + wn * 64 + nf * 16 + l15;
      const float bs = bias[col];
#pragma unroll
      for (int rf = 0; rf < 8; ++rf) {
#pragma unroll
        for (int r = 0; r < 4; ++r) {
          const int row = rt * 256 + wm * 128 + rf * 16 + quad * 4 + r;
          Out[(size_t)row * C_ + col] = acc[rf][nf][r] + bs;   // d_out is FP32
        }
      }
    }
  }
}

// ---------------- attention ----------------
// grid (256 bh, 8 qt): bh fastest -> all 8 qt-blocks of one bh on ONE XCD (K/V L2 reuse).
// block 256 = 4 waves x 32 q-rows. Swapped QK^T with PERMUTED K-row feed:
// mfma #ct2 reads K LDS rows perm(ct2,i) = 8*(i>>2)+(i&3)+{0,4,32,36}[ct2] (A-row i=l15),
// so lane (quad,l15) emerges holding P[q=l15][m in [8q,8q+8) u [32+8q,32+8q+8)] --
// exactly its PV A-frag set. cvt_pk packs mfma outputs DIRECTLY into A-frag words:
// zero cross-lane exchange (replaces 32 ds_bpermute + 16 cndmask per chunk; DS pipe
// was the top pipe at ~68%). Seg-swizzle keys on row bits 1,3 (perm freezes bit2):
// K-read -> l15 bits 1,2; V-read -> l15 bits 1,3; both 2 lanes/bank (free).
// No validity mask (pad K rows = 0 -> P=1, V pad = 0; den -= 48 exact).
__global__ __launch_bounds__(256) void attn_kernel(const unsigned short* __restrict__ Qt,
                                                   const unsigned short* __restrict__ Kw,
                                                   const unsigned short* __restrict__ Vt,
                                                   unsigned short* __restrict__ Ao) {
  __shared__ unsigned short Ks[2][4096];   // [buf][2 panels [64 m][32 d]], seg-swizzled
  __shared__ unsigned short Vs[2][4096];   // [buf][2 panels [64 d][32 m]], seg-swizzled
  const int tid = threadIdx.x;
  const int w = tid >> 6, lane = tid & 63;
  const int l15 = lane & 15, quad = lane >> 4, q8 = quad * 8;
  const int bh = blockIdx.x, qt = blockIdx.y;

  // Q B-frags from Q^T[bh][d][n]: lane = q-col = l15, k-elem j of half h = d = h*32+q8+j
  short8 aq[2][2];
#pragma unroll
  for (int mq = 0; mq < 2; ++mq) {
    int qrow = qt * 128 + w * 32 + mq * 16 + l15;
    const unsigned short* Qb = Qt + (size_t)bh * D_ * N_ + qrow;
#pragma unroll
    for (int h = 0; h < 2; ++h)
#pragma unroll
      for (int j = 0; j < 8; ++j)
        aq[mq][h][j] = (short)Qb[(size_t)(h * 32 + q8 + j) * N_];
  }

  f32x4 oacc[2][4] = {};
  float den[2] = {};

  const unsigned short* Kbh = Kw + (size_t)bh * MP_ * 64;
  const unsigned short* Vbh = Vt + (size_t)bh * 64 * MP_;

  // staging: lane -> (row-in-slot = lane>>2); source seg inverse-swizzled on row bits
  // 1,3 of LDS row R = w*16+(lane>>2): bit1 = lane bit3, bit3 = lane bit5.
  const int mrow = w * 16 + (lane >> 2);
  const int sw2 = (lane & 3) ^ (((lane >> 3) & 1) | (((lane >> 5) & 1) << 1));
  // K-frag read: permuted row base (R bits 1,3 = l15 bits 1,2); V-frag: straight rows
  const int krow = ((l15 >> 2) << 3) + (l15 & 3);
  const int qk_off = (quad ^ (((l15 >> 1) & 1) | (((l15 >> 2) & 1) << 1))) << 4;
  const int qv_off = (quad ^ (((l15 >> 1) & 1) | (((l15 >> 3) & 1) << 1))) << 4;

#define STAGE_KV(CH, BUF) {                                                    \
    _Pragma("unroll") for (int r = 0; r < 2; ++r) {                            \
      async_cp16(&Ks[BUF][r * 2048 + w * 512],                                 \
                 Kbh + (size_t)((CH) * 64 + mrow) * 64 + r * 32 + sw2 * 8);    \
      async_cp16(&Vs[BUF][r * 2048 + w * 512],                                 \
                 Vbh + (size_t)mrow * MP_ + (CH) * 64 + r * 32 + sw2 * 8);     \
    } }

  STAGE_KV(0, 0);

  union PAB { unsigned int u[4]; short8 s8; };

#pragma unroll 1
  for (int ch = 0; ch < 17; ++ch) {
    __syncthreads();   // vmcnt(0)+lgkmcnt(0)+barrier: buf[ch&1] landed for ALL waves;
                       // all waves finished reading buf[(ch+1)&1] in their iter ch-1
    if (ch + 1 < 17) STAGE_KV(ch + 1, (ch + 1) & 1);   // latency hides under compute(ch)

    const char* Kb = (const char*)&Ks[ch & 1][0];
    const char* Vb = (const char*)&Vs[ch & 1][0];

    // QK^T (swapped, permuted): output lane (quad,l15) reg r = P[q=l15][m=8q+r+c[ct2]]
    PAB apu[2][2];
#pragma unroll
    for (int ct2 = 0; ct2 < 4; ++ct2) {
      const int cc = (ct2 & 1) * 4 + (ct2 >> 1) * 32;      // {0,4,32,36}
      short8 k0 = *(const short8*)(Kb + (krow + cc) * 64 + qk_off);          // d 0..31
      short8 k1 = *(const short8*)(Kb + 4096 + (krow + cc) * 64 + qk_off);   // d 32..63
#pragma unroll
      for (int mq = 0; mq < 2; ++mq) {
        f32x4 s = {};
        s = __builtin_amdgcn_mfma_f32_16x16x32_bf16(k0, aq[mq][0], s, 0, 0, 0);
        s = __builtin_amdgcn_mfma_f32_16x16x32_bf16(k1, aq[mq][1], s, 0, 0, 0);
        float p0 = exp2_hw(s[0]), p1 = exp2_hw(s[1]);
        float p2 = exp2_hw(s[2]), p3 = exp2_hw(s[3]);
        den[mq] += (p0 + p1) + (p2 + p3);
        apu[mq][ct2 >> 1].u[(ct2 & 1) * 2]     = cvt_pk_bf16(p0, p1);
        apu[mq][ct2 >> 1].u[(ct2 & 1) * 2 + 1] = cvt_pk_bf16(p2, p3);
      }
    }

    // PV: A=P (rows=q, k=m lane-local), B=V^T (cols=d); panel h covers m in [32h,32h+32)
#pragma unroll
    for (int dt = 0; dt < 4; ++dt) {
      short8 b0 = *(const short8*)(Vb + (dt * 16 + l15) * 64 + qv_off);          // m 0..31
      short8 b1 = *(const short8*)(Vb + 4096 + (dt * 16 + l15) * 64 + qv_off);   // m 32..63
#pragma unroll
      for (int mq = 0; mq < 2; ++mq) {
        oacc[mq][dt] = __builtin_amdgcn_mfma_f32_16x16x32_bf16(apu[mq][0].s8, b0, oacc[mq][dt], 0, 0, 0);
        oacc[mq][dt] = __builtin_amdgcn_mfma_f32_16x16x32_bf16(apu[mq][1].s8, b1, oacc[mq][dt], 0, 0, 0);
      }
    }
  }
#undef STAGE_KV

  // den: each lane holds the partial over its own m-set for q=l15; quads partition m.
#pragma unroll
  for (int mq = 0; mq < 2; ++mq) {
    float d2 = den[mq];
    d2 += __shfl_xor(d2, 16);
    d2 += __shfl_xor(d2, 32);
    den[mq] = d2 - 48.0f;      // remove exp2(0)=1 from the 48 zero-pad rows (exact)
  }

  // broadcast den to output layout (row = quad*4+r) and normalize
  float rin[2][4];
#pragma unroll
  for (int mq = 0; mq < 2; ++mq)
#pragma unroll
    for (int r = 0; r < 4; ++r)
      rin[mq][r] = 1.f / __shfl(den[mq], quad * 4 + r);

  int b = bh >> 4, h = bh & 15;
#pragma unroll
  for (int mq = 0; mq < 2; ++mq)
#pragma unroll
    for (int dt = 0; dt < 4; ++dt)
#pragma unroll
      for (int r = 0; r < 4; ++r) {
        int qrow = qt * 128 + w * 32 + mq * 16 + quad * 4 + r;
        size_t dst = ((size_t)(b * N_ + qrow)) * C_ + h * 64 + dt * 16 + l15;
        Ao[dst] = f2bf(oacc[mq][dt][r] * rin[mq][r]);
      }
}

// ---------------- launch ----------------

extern "C" void kernel_launch(void* const* d_in, const int* in_sizes, int n_in,
                              void* d_out, int out_size, void* d_ws, size_t ws_size,
                              hipStream_t stream) {
  const float* x      = (const float*)d_in[0];
  const float* pk     = (const float*)d_in[1];
  const float* pv     = (const float*)d_in[2];
  const float* w_qkv  = (const float*)d_in[3];
  const float* w_proj = (const float*)d_in[4];
  const float* b_proj = (const float*)d_in[5];

  char* ws = (char*)d_ws;
  unsigned short* xb     = (unsigned short*)(ws);                 // 33,554,432 B
  unsigned short* wqkvT  = (unsigned short*)(ws + 33554432);      //  6,291,456 B
  unsigned short* wprojT = (unsigned short*)(ws + 39845888);      //  2,097,152 B
  unsigned short* Qt     = (unsigned short*)(ws + 41943040);      // 33,554,432 B
  unsigned short* Kw     = (unsigned short*)(ws + 75497472);      // 35,651,584 B
  unsigned short* Vt     = (unsigned short*)(ws + 111149056);     // 35,651,584 B
  unsigned short* attn   = xb;  // alias: xb is dead after the QKV GEMM

  prep_kernel<<<20480, 256, 0, stream>>>(x, pk, pv, xb, Kw, Vt);
  transpose_cast_kernel<<<dim3(64, 16), 256, 0, stream>>>(w_qkv, w_proj, wqkvT, wprojT);

  gemm256<0><<<dim3(64, 12), 512, 0, stream>>>(xb, wqkvT, Qt, Kw, Vt, nullptr, nullptr);
  attn_kernel<<<dim3(256, 8), 256, 0, stream>>>(Qt, Kw, Vt, attn);
  gemm256<1><<<dim3(64, 4), 512, 0, stream>>>(attn, wprojT, nullptr, nullptr, nullptr,
                                              b_proj, (float*)d_out);
}